// Round 1
// baseline (715.838 us; speedup 1.0000x reference)
//
#include <hip/hip_runtime.h>
#include <math.h>

#define BATCH 4
#define KQ    2048
#define NPTS  4096
#define CIN   61
#define KNN   32
#define ROWS  (BATCH*KQ*KNN)   // 262144

// ---------------- ws layout ----------------
// [0, 1MB)            : idx  int32 [ROWS]
// [1MB, +256)         : bn sum    f32[64]
// [1MB+256, +256)     : bn sumsq  f32[64]
// [1MB+512, +256)     : sA = gamma*invstd f32[64]
// [1MB+768, +1024)    : attA f32[64*4]
#define OFF_SUM 1048576

// ============ kNN: top-32 smallest d^2 via bit binary search ============
__global__ __launch_bounds__(256) void topk_kernel(
    const float* __restrict__ keys, const float* __restrict__ points,
    int* __restrict__ idx_out) {
  __shared__ unsigned int d2[NPTS];
  __shared__ int red[4];
  __shared__ int claim;
  const int tid = threadIdx.x;
  const int b = blockIdx.x >> 11;
  const int q = blockIdx.x & (KQ - 1);
  const float kx = keys[(b*KQ+q)*3+0];
  const float ky = keys[(b*KQ+q)*3+1];
  const float kz = keys[(b*KQ+q)*3+2];
  const float* __restrict__ P = points + (size_t)b * NPTS * 3;
  for (int n = tid; n < NPTS; n += 256) {
    float dx = P[n*3+0]-kx, dy = P[n*3+1]-ky, dz = P[n*3+2]-kz;
    d2[n] = __float_as_uint(dx*dx + dy*dy + dz*dz);  // >=0: uint order == float order
  }
  if (tid == 0) claim = 0;
  __syncthreads();
  unsigned lo = 0u, hi = 0x7f7fffffu;   // max finite float
  while (lo < hi) {
    unsigned mid = lo + ((hi - lo) >> 1);
    int c = 0;
    for (int n = tid; n < NPTS; n += 256) c += (d2[n] <= mid) ? 1 : 0;
    for (int off = 32; off > 0; off >>= 1) c += __shfl_down(c, off);
    if ((tid & 63) == 0) red[tid >> 6] = c;
    __syncthreads();
    int total = red[0] + red[1] + red[2] + red[3];
    __syncthreads();
    if (total >= KNN) hi = mid; else lo = mid + 1;
  }
  const unsigned T = hi;   // 32nd smallest
  for (int n = tid; n < NPTS; n += 256) {
    if (d2[n] <= T) {
      int pos = atomicAdd(&claim, 1);
      if (pos < KNN) idx_out[((size_t)(b*KQ+q))*KNN + pos] = n;
    }
  }
}

// ============ attA[c][h] = sum_d att_w[c, h*64+d] * att_q[h,d], c<64 ============
__global__ __launch_bounds__(256) void att_pre_kernel(
    const float* __restrict__ att_w, const float* __restrict__ att_q,
    float* __restrict__ attA) {
  const int t = threadIdx.x;       // 256 = 64 c * 4 h
  const int c = t >> 2, h = t & 3;
  float s = 0.f;
  for (int d = 0; d < 64; ++d)
    s += att_w[c*256 + h*64 + d] * att_q[h*64 + d];
  attA[c*4 + h] = s;
}

// ============ BN batch stats over gathered comb rows ============
__global__ __launch_bounds__(256) void bn_stats_kernel(
    const float* __restrict__ keys, const float* __restrict__ points,
    const float* __restrict__ feats, const int* __restrict__ idx,
    float* __restrict__ bnsum, float* __restrict__ bnsumsq) {
  __shared__ float ls[4][64];
  __shared__ float ls2[4][64];
  const int tid = threadIdx.x;
  const int c  = tid & 63;
  const int rl = tid >> 6;
  float s = 0.f, s2 = 0.f;
  for (int row = blockIdx.x * 4 + rl; row < ROWS; row += gridDim.x * 4) {
    int b = row >> 16;            // / (KQ*KNN)
    int rem = row & 65535;
    int q = rem >> 5;
    int n = idx[row];
    float v;
    if (c < 3) v = points[((size_t)b*NPTS + n)*3 + c] - keys[((size_t)b*KQ + q)*3 + c];
    else       v = feats[((size_t)b*NPTS + n)*CIN + (c-3)];
    s += v; s2 += v*v;
  }
  ls[rl][c] = s; ls2[rl][c] = s2;
  __syncthreads();
  if (tid < 64) {
    float ts  = ls[0][tid]+ls[1][tid]+ls[2][tid]+ls[3][tid];
    float ts2 = ls2[0][tid]+ls2[1][tid]+ls2[2][tid]+ls2[3][tid];
    atomicAdd(&bnsum[tid], ts);
    atomicAdd(&bnsumsq[tid], ts2);
  }
}

__global__ void bn_final_kernel(const float* __restrict__ bnsum,
                                const float* __restrict__ bnsumsq,
                                const float* __restrict__ gamma,
                                float* __restrict__ sA) {
  const int t = threadIdx.x;
  if (t < 64) {
    const float invR = 1.f / (float)ROWS;
    float mean = bnsum[t] * invR;
    float var  = bnsumsq[t] * invR - mean * mean;
    sA[t] = gamma[t] * rsqrtf(var + 1e-5f);
  }
}

// ============ per-query tiled GEMM helper ============
// C[32][No] = act(A[32][Ka] @ W[Ka][No] + bias). A,C in LDS; W,bias in global.
// 256 threads: lane jl = tid&63 owns columns {jl, jl+64}[:No/64];
// row-group rb = tid>>6 owns rows rb*8 .. rb*8+7. LDS A-reads are wave-broadcast.
template<int Ka, int No, bool RELU>
__device__ __forceinline__ void mm_tile(const float* As, int sA,
    const float* __restrict__ W, const float* __restrict__ bias,
    float* Cs, int sC, int tid) {
  constexpr int JB = No / 64;
  const int jl = tid & 63;
  const int r0 = (tid >> 6) * 8;
  float acc[8][JB];
#pragma unroll
  for (int i = 0; i < 8; ++i) {
#pragma unroll
    for (int k = 0; k < JB; ++k) acc[i][k] = bias[jl + 64*k];
  }
  for (int c = 0; c < Ka; c += 4) {
    float4 a[8];
#pragma unroll
    for (int i = 0; i < 8; ++i)
      a[i] = *reinterpret_cast<const float4*>(As + (r0+i)*sA + c);
#pragma unroll
    for (int cc = 0; cc < 4; ++cc) {
      float w[JB];
#pragma unroll
      for (int k = 0; k < JB; ++k) w[k] = W[(c+cc)*No + jl + 64*k];
#pragma unroll
      for (int i = 0; i < 8; ++i) {
        float av = (cc==0) ? a[i].x : (cc==1) ? a[i].y : (cc==2) ? a[i].z : a[i].w;
#pragma unroll
        for (int k = 0; k < JB; ++k) acc[i][k] = fmaf(av, w[k], acc[i][k]);
      }
    }
  }
#pragma unroll
  for (int i = 0; i < 8; ++i) {
#pragma unroll
    for (int k = 0; k < JB; ++k) {
      float v = acc[i][k];
      if (RELU) v = fmaxf(v, 0.f);
      Cs[(r0+i)*sC + jl + 64*k] = v;
    }
  }
}

// ============ fused main: gather -> e/softmax -> nx MLP -> weighted out ============
__global__ __launch_bounds__(256) void main_kernel(
    const float* __restrict__ keys, const float* __restrict__ points,
    const float* __restrict__ feats, const int* __restrict__ idx,
    const float* __restrict__ nx_w1, const float* __restrict__ nx_b1,
    const float* __restrict__ nx_w2, const float* __restrict__ nx_b2,
    const float* __restrict__ nx_w3, const float* __restrict__ nx_b3,
    const float* __restrict__ sA, const float* __restrict__ attA,
    float* __restrict__ out) {
  __shared__ __align__(16) float combS[32*68];   // comb, later lat
  __shared__ __align__(16) float B0[32*132];     // h1
  __shared__ __align__(16) float B1[32*132];     // h2
  __shared__ float AeS[64*4];
  __shared__ float eS[32*4];
  __shared__ float wS[32*4];
  __shared__ int idxS[32];
  const int tid = threadIdx.x;
  const int b = blockIdx.x >> 11;
  const int q = blockIdx.x & (KQ - 1);

  { // fold BN scale into attention vector: Ae[c][h] = sA[c]*attA[c][h]
    int c = tid >> 2, h = tid & 3;
    AeS[tid] = sA[c] * attA[c*4 + h];
  }
  if (tid < KNN) idxS[tid] = idx[((size_t)(b*KQ+q))*KNN + tid];
  __syncthreads();

  // gather comb [32 x 64] (rel | feats)
  for (int i = tid; i < 32*64; i += 256) {
    int r = i >> 6, c = i & 63;
    int n = idxS[r];
    float v;
    if (c < 3) v = points[((size_t)b*NPTS + n)*3 + c] - keys[((size_t)b*KQ + q)*3 + c];
    else       v = feats[((size_t)b*NPTS + n)*CIN + (c-3)];
    combS[r*68 + c] = v;
  }
  __syncthreads();

  // attention logits: e[n][h] = sum_c comb[n][c] * Ae[c][h]
  // (set_feat / att_b / BN-shift terms are n-constant -> cancel in softmax)
  if (tid < 128) {
    int n = tid >> 2, h = tid & 3;
    float e = 0.f;
    for (int c = 0; c < 64; ++c) e += combS[n*68 + c] * AeS[c*4 + h];
    eS[n*4 + h] = e;
  }
  __syncthreads();

  // softmax over neighbors (4 threads; overlaps with mm1 below)
  if (tid < 4) {
    float m = -1e30f;
    for (int n = 0; n < 32; ++n) m = fmaxf(m, eS[n*4 + tid]);
    float s = 0.f;
    for (int n = 0; n < 32; ++n) { float v = __expf(eS[n*4 + tid] - m); wS[n*4 + tid] = v; s += v; }
    float inv = 1.f / s;
    for (int n = 0; n < 32; ++n) wS[n*4 + tid] *= inv;
  }

  // nx MLP: 64 ->128 relu ->128 relu ->64
  mm_tile<64, 128, true >(combS, 68, nx_w1, nx_b1, B0, 132, tid);
  __syncthreads();
  mm_tile<128,128, true >(B0, 132, nx_w2, nx_b2, B1, 132, tid);
  __syncthreads();
  mm_tile<128, 64, false>(B1, 132, nx_w3, nx_b3, combS, 68, tid);  // lat
  __syncthreads();

  // out[o][h] = sum_n lat[n][o] * w[n][h]
  {
    int o = tid >> 2, h = tid & 3;
    float acc = 0.f;
    for (int n = 0; n < 32; ++n) acc += combS[n*68 + o] * wS[n*4 + h];
    out[(((size_t)(b*KQ + q))*64 + o)*4 + h] = acc;
  }
}

extern "C" void kernel_launch(void* const* d_in, const int* in_sizes, int n_in,
                              void* d_out, int out_size, void* d_ws, size_t ws_size,
                              hipStream_t stream) {
  const float* keys   = (const float*)d_in[0];
  const float* points = (const float*)d_in[1];
  const float* feats  = (const float*)d_in[2];
  const float* nx_w1  = (const float*)d_in[3];
  const float* nx_b1  = (const float*)d_in[4];
  const float* nx_w2  = (const float*)d_in[5];
  const float* nx_b2  = (const float*)d_in[6];
  const float* nx_w3  = (const float*)d_in[7];
  const float* nx_b3  = (const float*)d_in[8];
  // sx_w*/sx_b* (9..14), att_b (16), bn_beta (19): provably dead -> unused
  const float* att_w  = (const float*)d_in[15];
  const float* att_q  = (const float*)d_in[17];
  const float* gamma  = (const float*)d_in[18];
  float* out = (float*)d_out;

  char* ws = (char*)d_ws;
  int*   idx     = (int*)(ws + 0);
  float* bnsum   = (float*)(ws + OFF_SUM);
  float* bnsumsq = (float*)(ws + OFF_SUM + 256);
  float* sA      = (float*)(ws + OFF_SUM + 512);
  float* attA    = (float*)(ws + OFF_SUM + 768);

  hipMemsetAsync(bnsum, 0, 512, stream);
  topk_kernel<<<BATCH*KQ, 256, 0, stream>>>(keys, points, idx);
  att_pre_kernel<<<1, 256, 0, stream>>>(att_w, att_q, attA);
  bn_stats_kernel<<<1024, 256, 0, stream>>>(keys, points, feats, idx, bnsum, bnsumsq);
  bn_final_kernel<<<1, 64, 0, stream>>>(bnsum, bnsumsq, gamma, sA);
  main_kernel<<<BATCH*KQ, 256, 0, stream>>>(keys, points, feats, idx,
      nx_w1, nx_b1, nx_w2, nx_b2, nx_w3, nx_b3, sA, attA, out);
}

// Round 2
// 401.636 us; speedup vs baseline: 1.7823x; 1.7823x over previous
//
#include <hip/hip_runtime.h>
#include <math.h>

#define BATCH 4
#define KQ    2048
#define NPTS  4096
#define CIN   61
#define KNN   32
#define ROWS  (BATCH*KQ*KNN)   // 262144

// ---------------- ws layout (bytes) ----------------
// [0, 524288)       : idx  u16 [ROWS]
// 524288            : bn sum    f32[64]
// 524544            : bn sumsq  f32[64]
// 524800            : sA = gamma*invstd f32[64]
// 525056            : attA f32[64*4]
// 526336            : w1t_hi bf16 [128][64]   (16384 B)
// 542720            : w1t_lo
// 559104            : w2t_hi bf16 [128][128]  (32768 B)
// 591872            : w2t_lo
// 624640            : w3t_hi bf16 [64][128]   (16384 B)
// 641024            : w3t_lo          (end 657408)
#define OFF_SUM  524288
#define OFF_W1H  526336
#define OFF_W1L  542720
#define OFF_W2H  559104
#define OFF_W2L  591872
#define OFF_W3H  624640
#define OFF_W3L  641024

typedef __attribute__((ext_vector_type(8))) short bfrag;   // 8 bf16
typedef __attribute__((ext_vector_type(4))) float ffrag;   // 4 f32 acc

__device__ __forceinline__ unsigned short bf16_rne(float x) {
  unsigned u = __float_as_uint(x);
  unsigned r = u + 0x7fffu + ((u >> 16) & 1u);
  return (unsigned short)(r >> 16);
}
__device__ __forceinline__ float bf16_dec(unsigned short h) {
  return __uint_as_float(((unsigned)h) << 16);
}

// ============ kNN: top-32 smallest d^2, d2 register-resident ============
__global__ __launch_bounds__(256) void topk_kernel(
    const float* __restrict__ keys, const float* __restrict__ points,
    unsigned short* __restrict__ idx_out) {
  __shared__ int red[4];
  __shared__ int claim;
  const int tid = threadIdx.x;
  const int lane = tid & 63, wid = tid >> 6;
  const int b = blockIdx.x >> 11;
  const int q = blockIdx.x & (KQ - 1);
  const float kx = keys[(b*KQ+q)*3+0];
  const float ky = keys[(b*KQ+q)*3+1];
  const float kz = keys[(b*KQ+q)*3+2];
  const float* __restrict__ P = points + (size_t)b * NPTS * 3;
  unsigned u[16];
#pragma unroll
  for (int j = 0; j < 16; ++j) {
    int n = (j << 8) + tid;
    float dx = P[n*3+0]-kx, dy = P[n*3+1]-ky, dz = P[n*3+2]-kz;
    u[j] = __float_as_uint(dx*dx + dy*dy + dz*dz);   // >=0: uint order == float order
  }
  if (tid == 0) claim = 0;
  unsigned lo = 0u, hi = 0x7f7fffffu;
  while (lo < hi) {
    unsigned mid = lo + ((hi - lo) >> 1);
    int c = 0;
#pragma unroll
    for (int j = 0; j < 16; ++j) c += (u[j] <= mid) ? 1 : 0;
    for (int off = 32; off > 0; off >>= 1) c += __shfl_down(c, off);
    if (lane == 0) red[wid] = c;
    __syncthreads();
    int total = red[0] + red[1] + red[2] + red[3];
    __syncthreads();
    if (total >= KNN) hi = mid; else lo = mid + 1;
  }
  const unsigned T = hi;   // 32nd smallest
#pragma unroll
  for (int j = 0; j < 16; ++j) {
    if (u[j] <= T) {
      int pos = atomicAdd(&claim, 1);
      if (pos < KNN) idx_out[((size_t)(b*KQ+q))*KNN + pos] = (unsigned short)((j << 8) + tid);
    }
  }
}

// ============ attA[c][h] = sum_d att_w[c, h*64+d] * att_q[h,d], c<64 ============
__global__ __launch_bounds__(256) void att_pre_kernel(
    const float* __restrict__ att_w, const float* __restrict__ att_q,
    float* __restrict__ attA) {
  const int t = threadIdx.x;
  const int c = t >> 2, h = t & 3;
  float s = 0.f;
  for (int d = 0; d < 64; ++d)
    s += att_w[c*256 + h*64 + d] * att_q[h*64 + d];
  attA[c*4 + h] = s;
}

// ============ weights -> transposed bf16 hi/lo [N][K] ============
__global__ __launch_bounds__(256) void conv_w_kernel(
    const float* __restrict__ w1, const float* __restrict__ w2, const float* __restrict__ w3,
    short* __restrict__ w1h, short* __restrict__ w1l,
    short* __restrict__ w2h, short* __restrict__ w2l,
    short* __restrict__ w3h, short* __restrict__ w3l) {
  int t = blockIdx.x * 256 + threadIdx.x;   // 32768 total
  float v; short* ph; short* pl; int o;
  if (t < 8192)       { int n = t >> 6, k = t & 63;                 v = w1[k*128+n]; ph = w1h; pl = w1l; o = t; }
  else if (t < 24576) { int t2 = t-8192;  int n = t2 >> 7, k = t2 & 127; v = w2[k*128+n]; ph = w2h; pl = w2l; o = t2; }
  else                { int t3 = t-24576; int n = t3 >> 7, k = t3 & 127; v = w3[k*64+n];  ph = w3h; pl = w3l; o = t3; }
  unsigned short h = bf16_rne(v);
  ph[o] = (short)h;
  pl[o] = (short)bf16_rne(v - bf16_dec(h));
}

// ============ BN batch stats over gathered comb rows ============
__global__ __launch_bounds__(256) void bn_stats_kernel(
    const float* __restrict__ keys, const float* __restrict__ points,
    const float* __restrict__ feats, const unsigned short* __restrict__ idx,
    float* __restrict__ bnsum, float* __restrict__ bnsumsq) {
  __shared__ float ls[4][64];
  __shared__ float ls2[4][64];
  const int tid = threadIdx.x;
  const int c  = tid & 63;
  const int rl = tid >> 6;
  float s = 0.f, s2 = 0.f;
  for (int row = blockIdx.x * 4 + rl; row < ROWS; row += gridDim.x * 4) {
    int b = row >> 16;
    int rem = row & 65535;
    int q = rem >> 5;
    int n = idx[row];
    float v;
    if (c < 3) v = points[((size_t)b*NPTS + n)*3 + c] - keys[((size_t)b*KQ + q)*3 + c];
    else       v = feats[((size_t)b*NPTS + n)*CIN + (c-3)];
    s += v; s2 += v*v;
  }
  ls[rl][c] = s; ls2[rl][c] = s2;
  __syncthreads();
  if (tid < 64) {
    float ts  = ls[0][tid]+ls[1][tid]+ls[2][tid]+ls[3][tid];
    float ts2 = ls2[0][tid]+ls2[1][tid]+ls2[2][tid]+ls2[3][tid];
    atomicAdd(&bnsum[tid], ts);
    atomicAdd(&bnsumsq[tid], ts2);
  }
}

__global__ void bn_final_kernel(const float* __restrict__ bnsum,
                                const float* __restrict__ bnsumsq,
                                const float* __restrict__ gamma,
                                float* __restrict__ sA) {
  const int t = threadIdx.x;
  if (t < 64) {
    const float invR = 1.f / (float)ROWS;
    float mean = bnsum[t] * invR;
    float var  = bnsumsq[t] * invR - mean * mean;
    sA[t] = gamma[t] * rsqrtf(var + 1e-5f);
  }
}

// ============ per-wave split-bf16 MFMA GEMM ============
// wave owns 32 rows (2 m-tiles) in ACTW (hi at 0, lo at +4352 shorts, stride 136).
// W is bf16 hi/lo transposed [N][K]. Output: either back into ACTW (hi/lo bf16,
// relu+bias) or f32 into LATW (stride 68). 3-term split product: hh + hl + lh.
template<int K, int NT, bool OUTF32, bool RELU>
__device__ __forceinline__ void wave_gemm(short* ACTW,
    const short* __restrict__ WH, const short* __restrict__ WL,
    const float* __restrict__ bias, float* LATW, int lane) {
  const int lm = lane & 15, lq = lane >> 4;
  constexpr int KC = K / 32;
  bfrag ah[2][KC], al[2][KC];
#pragma unroll
  for (int mt = 0; mt < 2; ++mt)
#pragma unroll
    for (int kc = 0; kc < KC; ++kc) {
      const int a = (mt*16 + lm)*136 + kc*32 + lq*8;
      ah[mt][kc] = *(const bfrag*)(ACTW + a);
      al[mt][kc] = *(const bfrag*)(ACTW + 4352 + a);
    }
  ffrag acc[2][NT];
#pragma unroll
  for (int mt = 0; mt < 2; ++mt)
#pragma unroll
    for (int nt = 0; nt < NT; ++nt) acc[mt][nt] = (ffrag){0.f, 0.f, 0.f, 0.f};
#pragma unroll
  for (int kc = 0; kc < KC; ++kc) {
#pragma unroll
    for (int nt = 0; nt < NT; ++nt) {
      const int n = nt*16 + lm;
      const int wa = n*K + kc*32 + lq*8;
      bfrag bh = *(const bfrag*)(WH + wa);
      bfrag bl = *(const bfrag*)(WL + wa);
#pragma unroll
      for (int mt = 0; mt < 2; ++mt) {
        acc[mt][nt] = __builtin_amdgcn_mfma_f32_16x16x32_bf16(ah[mt][kc], bh, acc[mt][nt], 0, 0, 0);
        acc[mt][nt] = __builtin_amdgcn_mfma_f32_16x16x32_bf16(al[mt][kc], bh, acc[mt][nt], 0, 0, 0);
        acc[mt][nt] = __builtin_amdgcn_mfma_f32_16x16x32_bf16(ah[mt][kc], bl, acc[mt][nt], 0, 0, 0);
      }
    }
  }
  // all A-frag reads are consumed by MFMAs above (compiler-enforced lgkmcnt),
  // so in-place overwrite below is safe within the wave.
#pragma unroll
  for (int nt = 0; nt < NT; ++nt) {
    const int col = nt*16 + lm;
    const float bv = bias[col];
#pragma unroll
    for (int mt = 0; mt < 2; ++mt)
#pragma unroll
      for (int r = 0; r < 4; ++r) {
        const int row = mt*16 + lq*4 + r;
        float v = acc[mt][nt][r] + bv;
        if (RELU) v = fmaxf(v, 0.f);
        if (OUTF32) {
          LATW[row*68 + col] = v;
        } else {
          unsigned short h = bf16_rne(v);
          ACTW[row*136 + col] = (short)h;
          ACTW[4352 + row*136 + col] = (short)bf16_rne(v - bf16_dec(h));
        }
      }
  }
}

#define WAVE_SYNC() asm volatile("s_waitcnt lgkmcnt(0)" ::: "memory")

// ============ fused main: one query per wave, wave-synchronous ============
__global__ __launch_bounds__(256, 2) void main_kernel(
    const float* __restrict__ keys, const float* __restrict__ points,
    const float* __restrict__ feats, const unsigned short* __restrict__ idx,
    const short* __restrict__ w1h, const short* __restrict__ w1l,
    const short* __restrict__ w2h, const short* __restrict__ w2l,
    const short* __restrict__ w3h, const short* __restrict__ w3l,
    const float* __restrict__ nx_b1, const float* __restrict__ nx_b2,
    const float* __restrict__ nx_b3,
    const float* __restrict__ sA, const float* __restrict__ attA,
    float* __restrict__ out) {
  // LDS: 4 waves x (act hi/lo 17408B) = 69632 | Ae 1024 | 4 x scratch 2048
  __shared__ __align__(16) char smem[78848];
  const int tid = threadIdx.x;
  const int wid = tid >> 6, lane = tid & 63;
  const int b = blockIdx.x >> 9;                 // 512 blocks per batch
  const int qbase = (blockIdx.x & 511) * 4;
  const int q = qbase + wid;                     // this wave's query

  short* ACTW = (short*)smem + wid * 8704;       // hi [32][136]; lo at +4352
  float* LATW = (float*)(smem + wid * 17408);    // f32 [32][68] overlays ACTW
  float* Ae   = (float*)(smem + 69632);          // [64][4]
  float* EP   = (float*)(smem + 70656 + wid * 2048);  // epart [32][2][4]
  float* WS   = EP + 256;                        // softmax w [32][4]
  int*  IDXW  = (int*)(WS + 128);                // [32]

  const float* Pb = points + (size_t)b * NPTS * 3;
  const float* Kb = keys   + (size_t)b * KQ * 3;
  const float* Fb = feats  + (size_t)b * NPTS * CIN;

  // stage Ae (block-wide) + per-wave neighbor indices
  {
    int c = tid >> 2, h = tid & 3;
    Ae[tid] = sA[c] * attA[c*4 + h];
  }
  if (lane < KNN) IDXW[lane] = (int)idx[((size_t)(b*KQ + q))*KNN + lane];
  __syncthreads();   // the only block barrier

  // ---- gather comb -> hi/lo bf16 in ACTW; accumulate e-partials ----
  {
    const int rl = lane >> 1, half = lane & 1;
    const int n = IDXW[rl];
    float ep0 = 0.f, ep1 = 0.f, ep2 = 0.f, ep3 = 0.f;
#pragma unroll
    for (int cc = 0; cc < 32; ++cc) {
      const int c = half*32 + cc;
      float v;
      if (cc < 3 && half == 0) v = Pb[n*3 + c] - Kb[q*3 + c];
      else                     v = Fb[(size_t)n*CIN + (c-3)];
      unsigned short hbits = bf16_rne(v);
      float fh = bf16_dec(hbits);
      unsigned short lbits = bf16_rne(v - fh);
      ACTW[rl*136 + c] = (short)hbits;
      ACTW[4352 + rl*136 + c] = (short)lbits;
      float vq = fh + bf16_dec(lbits);           // what the GEMM sees
      ep0 = fmaf(vq, Ae[c*4+0], ep0);
      ep1 = fmaf(vq, Ae[c*4+1], ep1);
      ep2 = fmaf(vq, Ae[c*4+2], ep2);
      ep3 = fmaf(vq, Ae[c*4+3], ep3);
    }
    EP[rl*8 + half*4 + 0] = ep0;
    EP[rl*8 + half*4 + 1] = ep1;
    EP[rl*8 + half*4 + 2] = ep2;
    EP[rl*8 + half*4 + 3] = ep3;
  }
  WAVE_SYNC();

  // combine halves: e[r][h] = EP[r][0][h] + EP[r][1][h]  (kept at EP[r*8+h])
  {
    int i0 = lane * 2;
#pragma unroll
    for (int k = 0; k < 2; ++k) {
      int i = i0 + k;              // 0..127 -> (r,h)
      int r = i >> 2, h = i & 3;
      EP[r*8 + h] = EP[r*8 + h] + EP[r*8 + 4 + h];
    }
  }
  WAVE_SYNC();

  // softmax over neighbors per head (n-constant logit terms cancel)
  if (lane < 4) {
    const int h = lane;
    float m = -1e30f;
    for (int n = 0; n < KNN; ++n) m = fmaxf(m, EP[n*8 + h]);
    float s = 0.f;
    for (int n = 0; n < KNN; ++n) { float v = __expf(EP[n*8 + h] - m); WS[n*4 + h] = v; s += v; }
    float inv = 1.f / s;
    for (int n = 0; n < KNN; ++n) WS[n*4 + h] *= inv;
  }
  WAVE_SYNC();

  // ---- nx MLP on matrix cores (split-bf16): 64 ->128 relu ->128 relu ->64 ----
  wave_gemm<64, 8, false, true >(ACTW, w1h, w1l, nx_b1, LATW, lane);
  WAVE_SYNC();
  wave_gemm<128, 8, false, true >(ACTW, w2h, w2l, nx_b2, LATW, lane);
  WAVE_SYNC();
  wave_gemm<128, 4, true, false>(ACTW, w3h, w3l, nx_b3, LATW, lane);
  WAVE_SYNC();

  // ---- epilogue: out[o][h] = sum_n lat[n][o] * w[n][h] ----
  {
    const int o = lane;
    float a0 = 0.f, a1 = 0.f, a2 = 0.f, a3 = 0.f;
#pragma unroll
    for (int n = 0; n < KNN; ++n) {
      float l = LATW[n*68 + o];
      a0 = fmaf(l, WS[n*4+0], a0);
      a1 = fmaf(l, WS[n*4+1], a1);
      a2 = fmaf(l, WS[n*4+2], a2);
      a3 = fmaf(l, WS[n*4+3], a3);
    }
    float4 r; r.x = a0; r.y = a1; r.z = a2; r.w = a3;
    *(float4*)(out + (((size_t)(b*KQ + q))*64 + o)*4) = r;
  }
}

extern "C" void kernel_launch(void* const* d_in, const int* in_sizes, int n_in,
                              void* d_out, int out_size, void* d_ws, size_t ws_size,
                              hipStream_t stream) {
  const float* keys   = (const float*)d_in[0];
  const float* points = (const float*)d_in[1];
  const float* feats  = (const float*)d_in[2];
  const float* nx_w1  = (const float*)d_in[3];
  const float* nx_b1  = (const float*)d_in[4];
  const float* nx_w2  = (const float*)d_in[5];
  const float* nx_b2  = (const float*)d_in[6];
  const float* nx_w3  = (const float*)d_in[7];
  const float* nx_b3  = (const float*)d_in[8];
  // sx_w*/sx_b* (9..14), att_b (16), bn_beta (19): n-constant in the softmax -> dead
  const float* att_w  = (const float*)d_in[15];
  const float* att_q  = (const float*)d_in[17];
  const float* gamma  = (const float*)d_in[18];
  float* out = (float*)d_out;

  char* ws = (char*)d_ws;
  unsigned short* idx = (unsigned short*)(ws + 0);
  float* bnsum   = (float*)(ws + OFF_SUM);
  float* bnsumsq = (float*)(ws + OFF_SUM + 256);
  float* sA      = (float*)(ws + OFF_SUM + 512);
  float* attA    = (float*)(ws + OFF_SUM + 768 + 256);
  short* w1h = (short*)(ws + OFF_W1H);
  short* w1l = (short*)(ws + OFF_W1L);
  short* w2h = (short*)(ws + OFF_W2H);
  short* w2l = (short*)(ws + OFF_W2L);
  short* w3h = (short*)(ws + OFF_W3H);
  short* w3l = (short*)(ws + OFF_W3L);

  hipMemsetAsync(bnsum, 0, 512, stream);
  conv_w_kernel<<<128, 256, 0, stream>>>(nx_w1, nx_w2, nx_w3, w1h, w1l, w2h, w2l, w3h, w3l);
  att_pre_kernel<<<1, 256, 0, stream>>>(att_w, att_q, attA);
  topk_kernel<<<BATCH*KQ, 256, 0, stream>>>(keys, points, idx);
  bn_stats_kernel<<<1024, 256, 0, stream>>>(keys, points, feats, idx, bnsum, bnsumsq);
  bn_final_kernel<<<1, 64, 0, stream>>>(bnsum, bnsumsq, gamma, sA);
  main_kernel<<<BATCH*KQ/4, 256, 0, stream>>>(keys, points, feats, idx,
      w1h, w1l, w2h, w2l, w3h, w3l, nx_b1, nx_b2, nx_b3, sA, attA, out);
}

// Round 3
// 387.743 us; speedup vs baseline: 1.8462x; 1.0358x over previous
//
#include <hip/hip_runtime.h>
#include <math.h>

#define BATCH 4
#define KQ    2048
#define NPTS  4096
#define CIN   61
#define KNN   32
#define ROWS  (BATCH*KQ*KNN)   // 262144

// ---------------- ws layout (bytes) ----------------
#define OFF_SUM   524288   // bnsum f32[64]
#define OFF_SUMSQ 524544   // bnsumsq f32[64]
#define OFF_SA    524800   // sA f32[64]
#define OFF_ATTA  525056   // attA f32[256]
#define OFF_W1H   526336   // bf16 [128][64]
#define OFF_W1L   542720
#define OFF_W2H   559104   // bf16 [128][128]
#define OFF_W2L   591872
#define OFF_W3H   624640   // bf16 [64][128]
#define OFF_W3L   641024   // end 657408

typedef __attribute__((ext_vector_type(8))) short bfrag;   // 8 bf16
typedef __attribute__((ext_vector_type(4))) float ffrag;   // 4 f32 acc

__device__ __forceinline__ unsigned short bf16_rne(float x) {
  unsigned u = __float_as_uint(x);
  unsigned r = u + 0x7fffu + ((u >> 16) & 1u);
  return (unsigned short)(r >> 16);
}
__device__ __forceinline__ float bf16_dec(unsigned short h) {
  return __uint_as_float(((unsigned)h) << 16);
}
__device__ __forceinline__ float4 ld4u(const float* p) {  // 4B-aligned vec load
  float4 r; __builtin_memcpy(&r, p, 16); return r;
}

#define WAVE_SYNC() asm volatile("s_waitcnt lgkmcnt(0)" ::: "memory")

// ============ kNN: wave-per-query, register d^2, ballot counting ============
__global__ __launch_bounds__(256) void topk_kernel(
    const float* __restrict__ keys, const float* __restrict__ points,
    unsigned short* __restrict__ idx_out) {
  const int lane = threadIdx.x & 63, wid = threadIdx.x >> 6;
  const int g = blockIdx.x * 4 + wid;          // global query
  const int b = g >> 11;
  const int q = g & (KQ - 1);
  const float kx = keys[(size_t)g*3+0];
  const float ky = keys[(size_t)g*3+1];
  const float kz = keys[(size_t)g*3+2];
  const float* __restrict__ P = points + (size_t)b * NPTS * 3;
  unsigned u[64];
#pragma unroll
  for (int j = 0; j < 64; ++j) {
    int n = (j << 6) + lane;
    float dx = P[n*3+0]-kx, dy = P[n*3+1]-ky, dz = P[n*3+2]-kz;
    u[j] = __float_as_uint(dx*dx + dy*dy + dz*dz);  // >=0: uint order == float
  }
  unsigned lo = 0u, hi = 0x7f7fffffu;
  while (lo < hi) {
    unsigned mid = lo + ((hi - lo) >> 1);
    int total = 0;
#pragma unroll
    for (int j = 0; j < 64; ++j)
      total += (int)__popcll(__ballot(u[j] <= mid));
    if (total >= KNN) hi = mid; else lo = mid + 1;
  }
  const unsigned T = hi;   // exact 32nd-smallest d^2 bits
  const unsigned long long lmask = (1ull << lane) - 1ull;
  unsigned short* dst = idx_out + (size_t)g * KNN;
  int base = 0;
#pragma unroll
  for (int j = 0; j < 64; ++j) {
    unsigned long long m = __ballot(u[j] <= T);
    if (u[j] <= T) {
      int pos = base + (int)__popcll(m & lmask);
      if (pos < KNN) dst[pos] = (unsigned short)((j << 6) + lane);
    }
    base += (int)__popcll(m);
  }
}

// ============ prep: weight conv (blocks 0..127) + attA (block 128) ============
__global__ __launch_bounds__(256) void prep_kernel(
    const float* __restrict__ w1, const float* __restrict__ w2, const float* __restrict__ w3,
    const float* __restrict__ att_w, const float* __restrict__ att_q,
    short* __restrict__ w1h, short* __restrict__ w1l,
    short* __restrict__ w2h, short* __restrict__ w2l,
    short* __restrict__ w3h, short* __restrict__ w3l,
    float* __restrict__ attA) {
  if (blockIdx.x == 128) {   // attA[c][h] = sum_d att_w[c, h*64+d]*att_q[h,d]
    const int t = threadIdx.x, c = t >> 2, h = t & 3;
    float s = 0.f;
    for (int d = 0; d < 64; ++d) s += att_w[c*256 + h*64 + d] * att_q[h*64 + d];
    attA[c*4 + h] = s;
    return;
  }
  int t = blockIdx.x * 256 + threadIdx.x;   // 32768 total
  float v; short* ph; short* pl; int o;
  if (t < 8192)       { int n = t >> 6, k = t & 63;                  v = w1[k*128+n]; ph = w1h; pl = w1l; o = t;  }
  else if (t < 24576) { int t2 = t-8192;  int n = t2 >> 7, k = t2 & 127; v = w2[k*128+n]; ph = w2h; pl = w2l; o = t2; }
  else                { int t3 = t-24576; int n = t3 >> 7, k = t3 & 127; v = w3[k*64+n];  ph = w3h; pl = w3l; o = t3; }
  unsigned short h = bf16_rne(v);
  ph[o] = (short)h;
  pl[o] = (short)bf16_rne(v - bf16_dec(h));
}

// ============ BN batch stats over gathered comb rows ============
__global__ __launch_bounds__(256) void bn_stats_kernel(
    const float* __restrict__ keys, const float* __restrict__ points,
    const float* __restrict__ feats, const unsigned short* __restrict__ idx,
    float* __restrict__ bnsum, float* __restrict__ bnsumsq) {
  __shared__ float ls[4][64];
  __shared__ float ls2[4][64];
  const int tid = threadIdx.x;
  const int c  = tid & 63;
  const int rl = tid >> 6;
  float s = 0.f, s2 = 0.f;
  for (int row = blockIdx.x * 4 + rl; row < ROWS; row += gridDim.x * 4) {
    int b = row >> 16;
    int rem = row & 65535;
    int q = rem >> 5;
    int n = idx[row];
    float v;
    if (c < 3) v = points[((size_t)b*NPTS + n)*3 + c] - keys[((size_t)b*KQ + q)*3 + c];
    else       v = feats[((size_t)b*NPTS + n)*CIN + (c-3)];
    s += v; s2 += v*v;
  }
  ls[rl][c] = s; ls2[rl][c] = s2;
  __syncthreads();
  if (tid < 64) {
    float ts  = ls[0][tid]+ls[1][tid]+ls[2][tid]+ls[3][tid];
    float ts2 = ls2[0][tid]+ls2[1][tid]+ls2[2][tid]+ls2[3][tid];
    atomicAdd(&bnsum[tid], ts);
    atomicAdd(&bnsumsq[tid], ts2);
  }
}

__global__ void bn_final_kernel(const float* __restrict__ bnsum,
                                const float* __restrict__ bnsumsq,
                                const float* __restrict__ gamma,
                                float* __restrict__ sA) {
  const int t = threadIdx.x;
  if (t < 64) {
    const float invR = 1.f / (float)ROWS;
    float mean = bnsum[t] * invR;
    float var  = bnsumsq[t] * invR - mean * mean;
    sA[t] = gamma[t] * rsqrtf(var + 1e-5f);
  }
}

// ============ per-wave GEMM: plain-bf16 A (LDS), split hi/lo B (global) ======
// C = A @ (Bh+Bl) + bias. A: 32 rows, stride 136 shorts. NT processed in
// blocks of 4 to bound live acc VGPRs (4 blocks/CU needs <=128 VGPR).
template<int K, int NT, bool OUTF32, bool RELU>
__device__ __forceinline__ void wave_gemm(short* ACTW,
    const short* __restrict__ WH, const short* __restrict__ WL,
    const float* __restrict__ bias, float* LATW, int lane) {
  const int lm = lane & 15, lq = lane >> 4;
  constexpr int KC = K / 32;
  bfrag a[2][KC];
#pragma unroll
  for (int mt = 0; mt < 2; ++mt)
#pragma unroll
    for (int kc = 0; kc < KC; ++kc)
      a[mt][kc] = *(const bfrag*)(ACTW + (mt*16 + lm)*136 + kc*32 + lq*8);
#pragma unroll
  for (int nb = 0; nb < NT; nb += 4) {
    ffrag acc[2][4];
#pragma unroll
    for (int mt = 0; mt < 2; ++mt)
#pragma unroll
      for (int nt = 0; nt < 4; ++nt) acc[mt][nt] = (ffrag){0.f,0.f,0.f,0.f};
#pragma unroll
    for (int kc = 0; kc < KC; ++kc) {
#pragma unroll
      for (int nt = 0; nt < 4; ++nt) {
        const int n = (nb + nt)*16 + lm;
        const int wa = n*K + kc*32 + lq*8;
        bfrag bh = *(const bfrag*)(WH + wa);
        bfrag bl = *(const bfrag*)(WL + wa);
        acc[0][nt] = __builtin_amdgcn_mfma_f32_16x16x32_bf16(a[0][kc], bh, acc[0][nt], 0,0,0);
        acc[1][nt] = __builtin_amdgcn_mfma_f32_16x16x32_bf16(a[1][kc], bh, acc[1][nt], 0,0,0);
        acc[0][nt] = __builtin_amdgcn_mfma_f32_16x16x32_bf16(a[0][kc], bl, acc[0][nt], 0,0,0);
        acc[1][nt] = __builtin_amdgcn_mfma_f32_16x16x32_bf16(a[1][kc], bl, acc[1][nt], 0,0,0);
      }
    }
#pragma unroll
    for (int nt = 0; nt < 4; ++nt) {
      const int col = (nb + nt)*16 + lm;
      const float bv = bias[col];
#pragma unroll
      for (int mt = 0; mt < 2; ++mt)
#pragma unroll
        for (int r = 0; r < 4; ++r) {
          const int row = mt*16 + lq*4 + r;
          float v = acc[mt][nt][r] + bv;
          if (RELU) v = fmaxf(v, 0.f);
          if (OUTF32) LATW[row*68 + col] = v;
          else        ACTW[row*136 + col] = (short)bf16_rne(v);
        }
    }
  }
}

// ============ fused main: one query/wave, zero block barriers, 4 blocks/CU ====
__global__ __launch_bounds__(256, 4) void main_kernel(
    const float* __restrict__ keys, const float* __restrict__ points,
    const float* __restrict__ feats, const unsigned short* __restrict__ idx,
    const short* __restrict__ w1h, const short* __restrict__ w1l,
    const short* __restrict__ w2h, const short* __restrict__ w2l,
    const short* __restrict__ w3h, const short* __restrict__ w3l,
    const float* __restrict__ nx_b1, const float* __restrict__ nx_b2,
    const float* __restrict__ nx_b3,
    const float* __restrict__ sA, const float* __restrict__ attA,
    float* __restrict__ out) {
  // LDS: 4x ACT 8704 = 34816 | Ae 1024 | 4x scratch 1152 = 4608 -> 40448 B
  __shared__ __align__(16) char smem[40448];
  const int tid = threadIdx.x;
  const int wid = tid >> 6, lane = tid & 63;
  const int g = blockIdx.x * 4 + wid;            // this wave's query
  const int b = g >> 11;

  short* ACTW = (short*)(smem + wid * 8704);     // bf16 [32][136]
  float* LATW = (float*)(smem + wid * 8704);     // f32 [32][68] overlay
  float* Ae   = (float*)(smem + 34816);          // [64][4], redundantly staged
  float* EP   = (float*)(smem + 35840 + wid * 1152);  // [32][8]: e-parts | WS
  int*  IDXW  = (int*)(EP + 256);                // [32]

  const float* Pb = points + (size_t)b * NPTS * 3;
  const float* Fb = feats  + (size_t)b * NPTS * CIN;

  // stage Ae (each wave writes the full, identical table -> wave-sync only)
  {
    float s = sA[lane];
    float4 aq = ld4u(attA + lane*4);
    float4 r; r.x = s*aq.x; r.y = s*aq.y; r.z = s*aq.z; r.w = s*aq.w;
    *(float4*)(Ae + lane*4) = r;
  }
  if (lane < KNN) IDXW[lane] = (int)idx[(size_t)g*KNN + lane];
  WAVE_SYNC();

  // ---- gather comb -> bf16 A in LDS; e-partials on exact f32 values ----
  {
    const int rl = lane >> 1, half = lane & 1;
    const int n = IDXW[rl];
    const float* frow = Fb + (size_t)n * CIN;
    float v[32];
    if (half == 0) {
      v[0] = Pb[n*3+0] - keys[(size_t)g*3+0];
      v[1] = Pb[n*3+1] - keys[(size_t)g*3+1];
      v[2] = Pb[n*3+2] - keys[(size_t)g*3+2];
#pragma unroll
      for (int kk = 0; kk < 7; ++kk) {
        float4 t = ld4u(frow + kk*4);
        v[3+kk*4+0] = t.x; v[3+kk*4+1] = t.y; v[3+kk*4+2] = t.z; v[3+kk*4+3] = t.w;
      }
      v[31] = frow[28];
    } else {
#pragma unroll
      for (int kk = 0; kk < 8; ++kk) {
        float4 t = ld4u(frow + 29 + kk*4);
        v[kk*4+0] = t.x; v[kk*4+1] = t.y; v[kk*4+2] = t.z; v[kk*4+3] = t.w;
      }
    }
    float ep0 = 0.f, ep1 = 0.f, ep2 = 0.f, ep3 = 0.f;
#pragma unroll
    for (int cc = 0; cc < 32; ++cc) {
      float4 ae = *(const float4*)(Ae + (half*32 + cc)*4);
      ep0 = fmaf(v[cc], ae.x, ep0);
      ep1 = fmaf(v[cc], ae.y, ep1);
      ep2 = fmaf(v[cc], ae.z, ep2);
      ep3 = fmaf(v[cc], ae.w, ep3);
    }
#pragma unroll
    for (int k = 0; k < 4; ++k) {
      bfrag pk;
#pragma unroll
      for (int t = 0; t < 8; ++t) pk[t] = (short)bf16_rne(v[k*8 + t]);
      *(bfrag*)(ACTW + rl*136 + half*32 + k*8) = pk;
    }
    float4 e4; e4.x = ep0; e4.y = ep1; e4.z = ep2; e4.w = ep3;
    *(float4*)(EP + rl*8 + half*4) = e4;
  }
  WAVE_SYNC();

  // ---- parallel softmax over neighbors (n-constant logit terms cancel) ----
  {
    const int h = lane & 3, n0 = lane >> 2;      // lane covers n0 and n0+16
    float e0 = EP[n0*8 + h]      + EP[n0*8 + 4 + h];
    float e1 = EP[(n0+16)*8 + h] + EP[(n0+16)*8 + 4 + h];
    float m = fmaxf(e0, e1);
    m = fmaxf(m, __shfl_xor(m, 4));
    m = fmaxf(m, __shfl_xor(m, 8));
    m = fmaxf(m, __shfl_xor(m, 16));
    m = fmaxf(m, __shfl_xor(m, 32));
    float x0 = __expf(e0 - m), x1 = __expf(e1 - m);
    float s = x0 + x1;
    s += __shfl_xor(s, 4);
    s += __shfl_xor(s, 8);
    s += __shfl_xor(s, 16);
    s += __shfl_xor(s, 32);
    float inv = 1.f / s;
    EP[n0*8 + 4 + h]      = x0 * inv;            // WS[n][h] at EP[n*8+4+h]
    EP[(n0+16)*8 + 4 + h] = x1 * inv;
  }

  // ---- nx MLP on matrix cores: 64 ->128 relu ->128 relu ->64 ----
  wave_gemm<64, 8, false, true >(ACTW, w1h, w1l, nx_b1, LATW, lane);
  WAVE_SYNC();
  wave_gemm<128, 8, false, true >(ACTW, w2h, w2l, nx_b2, LATW, lane);
  WAVE_SYNC();
  wave_gemm<128, 4, true,  false>(ACTW, w3h, w3l, nx_b3, LATW, lane);
  WAVE_SYNC();

  // ---- epilogue: out[o][h] = sum_n lat[n][o] * w[n][h] ----
  {
    const int o = lane;
    float a0 = 0.f, a1 = 0.f, a2 = 0.f, a3 = 0.f;
#pragma unroll
    for (int n = 0; n < KNN; ++n) {
      float4 w = *(const float4*)(EP + n*8 + 4);   // broadcast read
      float l = LATW[n*68 + o];
      a0 = fmaf(l, w.x, a0);
      a1 = fmaf(l, w.y, a1);
      a2 = fmaf(l, w.z, a2);
      a3 = fmaf(l, w.w, a3);
    }
    float4 r; r.x = a0; r.y = a1; r.z = a2; r.w = a3;
    *(float4*)(out + ((size_t)g*64 + o)*4) = r;
  }
}

extern "C" void kernel_launch(void* const* d_in, const int* in_sizes, int n_in,
                              void* d_out, int out_size, void* d_ws, size_t ws_size,
                              hipStream_t stream) {
  const float* keys   = (const float*)d_in[0];
  const float* points = (const float*)d_in[1];
  const float* feats  = (const float*)d_in[2];
  const float* nx_w1  = (const float*)d_in[3];
  const float* nx_b1  = (const float*)d_in[4];
  const float* nx_w2  = (const float*)d_in[5];
  const float* nx_b2  = (const float*)d_in[6];
  const float* nx_w3  = (const float*)d_in[7];
  const float* nx_b3  = (const float*)d_in[8];
  // sx_w*/sx_b* (9..14), att_b (16), bn_beta (19): n-constant in softmax -> dead
  const float* att_w  = (const float*)d_in[15];
  const float* att_q  = (const float*)d_in[17];
  const float* gamma  = (const float*)d_in[18];
  float* out = (float*)d_out;

  char* ws = (char*)d_ws;
  unsigned short* idx = (unsigned short*)(ws + 0);
  float* bnsum   = (float*)(ws + OFF_SUM);
  float* bnsumsq = (float*)(ws + OFF_SUMSQ);
  float* sA      = (float*)(ws + OFF_SA);
  float* attA    = (float*)(ws + OFF_ATTA);
  short* w1h = (short*)(ws + OFF_W1H);
  short* w1l = (short*)(ws + OFF_W1L);
  short* w2h = (short*)(ws + OFF_W2H);
  short* w2l = (short*)(ws + OFF_W2L);
  short* w3h = (short*)(ws + OFF_W3H);
  short* w3l = (short*)(ws + OFF_W3L);

  hipMemsetAsync(bnsum, 0, 512, stream);
  prep_kernel<<<129, 256, 0, stream>>>(nx_w1, nx_w2, nx_w3, att_w, att_q,
                                       w1h, w1l, w2h, w2l, w3h, w3l, attA);
  topk_kernel<<<BATCH*KQ/4, 256, 0, stream>>>(keys, points, idx);
  bn_stats_kernel<<<1024, 256, 0, stream>>>(keys, points, feats, idx, bnsum, bnsumsq);
  bn_final_kernel<<<1, 64, 0, stream>>>(bnsum, bnsumsq, gamma, sA);
  main_kernel<<<BATCH*KQ/4, 256, 0, stream>>>(keys, points, feats, idx,
      w1h, w1l, w2h, w2l, w3h, w3l, nx_b1, nx_b2, nx_b3, sA, attA, out);
}

// Round 4
// 368.818 us; speedup vs baseline: 1.9409x; 1.0513x over previous
//
#include <hip/hip_runtime.h>
#include <math.h>

#define BATCH 4
#define KQ    2048
#define NPTS  4096
#define CIN   61
#define KNN   32
#define ROWS  (BATCH*KQ*KNN)   // 262144

// ---------------- ws layout (bytes) ----------------
#define OFF_SUM   524288   // bnsum f32[64]
#define OFF_SUMSQ 524544   // bnsumsq f32[64]
#define OFF_ATTA  524800   // attA f32[256]
#define OFF_W1H   526336   // bf16 [128][64]
#define OFF_W1L   542720   // (written by prep, unused by main)
#define OFF_W2H   559104   // bf16 [128][128]
#define OFF_W2L   591872
#define OFF_W3H   624640   // bf16 [64][128]
#define OFF_W3L   641024
#define OFF_PT    657408   // points SoA f32 [4][3][4096] = 196608
#define OFF_AE    854016   // Ae f32[256] = sA[c]*attA[c][h]   (end 855040)

typedef __attribute__((ext_vector_type(8))) short bfrag;   // 8 bf16
typedef __attribute__((ext_vector_type(4))) float ffrag;   // 4 f32 acc

__device__ __forceinline__ unsigned short bf16_rne(float x) {
  unsigned u = __float_as_uint(x);
  unsigned r = u + 0x7fffu + ((u >> 16) & 1u);
  return (unsigned short)(r >> 16);
}
__device__ __forceinline__ float bf16_dec(unsigned short h) {
  return __uint_as_float(((unsigned)h) << 16);
}
__device__ __forceinline__ float4 ld4u(const float* p) {  // 4B-aligned vec load
  float4 r; __builtin_memcpy(&r, p, 16); return r;
}

#define WAVE_SYNC() asm volatile("s_waitcnt lgkmcnt(0)" ::: "memory")

// ============ kNN: wave-per-query, SoA points (coalesced), ballot count ======
__global__ __launch_bounds__(256) void topk_kernel(
    const float* __restrict__ keys, const float* __restrict__ PT,
    unsigned short* __restrict__ idx_out) {
  const int lane = threadIdx.x & 63, wid = threadIdx.x >> 6;
  const int g = blockIdx.x * 4 + wid;          // global query
  const int b = g >> 11;
  const float kx = keys[(size_t)g*3+0];
  const float ky = keys[(size_t)g*3+1];
  const float kz = keys[(size_t)g*3+2];
  const float* __restrict__ Px = PT + (size_t)b * 3 * NPTS;
  const float* __restrict__ Py = Px + NPTS;
  const float* __restrict__ Pz = Py + NPTS;
  unsigned u[64];
#pragma unroll
  for (int j = 0; j < 64; ++j) {
    int n = (j << 6) + lane;
    float dx = Px[n]-kx, dy = Py[n]-ky, dz = Pz[n]-kz;
    u[j] = __float_as_uint(dx*dx + dy*dy + dz*dz);  // >=0: uint order == float
  }
  unsigned lo = 0u, hi = 0x7f7fffffu;
  while (lo < hi) {
    unsigned mid = lo + ((hi - lo) >> 1);
    int total = 0;
#pragma unroll
    for (int j = 0; j < 64; ++j)
      total += (int)__popcll(__ballot(u[j] <= mid));
    if (total >= KNN) hi = mid; else lo = mid + 1;
  }
  const unsigned T = hi;   // exact 32nd-smallest d^2 bits
  const unsigned long long lmask = (1ull << lane) - 1ull;
  unsigned short* dst = idx_out + (size_t)g * KNN;
  int base = 0;
#pragma unroll
  for (int j = 0; j < 64; ++j) {
    unsigned long long m = __ballot(u[j] <= T);
    if (u[j] <= T) {
      int pos = base + (int)__popcll(m & lmask);
      if (pos < KNN) dst[pos] = (unsigned short)((j << 6) + lane);
    }
    base += (int)__popcll(m);
  }
}

// ==== prep: weight conv (blocks 0..127) + attA (128) + SoA points (129..320) =
__global__ __launch_bounds__(256) void prep_kernel(
    const float* __restrict__ w1, const float* __restrict__ w2, const float* __restrict__ w3,
    const float* __restrict__ att_w, const float* __restrict__ att_q,
    const float* __restrict__ points,
    short* __restrict__ w1h, short* __restrict__ w1l,
    short* __restrict__ w2h, short* __restrict__ w2l,
    short* __restrict__ w3h, short* __restrict__ w3l,
    float* __restrict__ attA, float* __restrict__ PT) {
  if (blockIdx.x == 128) {   // attA[c][h] = sum_d att_w[c, h*64+d]*att_q[h,d]
    const int t = threadIdx.x, c = t >> 2, h = t & 3;
    float s = 0.f;
    for (int d = 0; d < 64; ++d) s += att_w[c*256 + h*64 + d] * att_q[h*64 + d];
    attA[c*4 + h] = s;
    return;
  }
  if (blockIdx.x >= 129) {   // points AoS -> SoA
    int t = (blockIdx.x - 129) * 256 + threadIdx.x;   // < 49152
    int b = t / 12288, rem = t % 12288, c = rem >> 12, n = rem & 4095;
    PT[t] = points[((size_t)b*NPTS + n)*3 + c];
    return;
  }
  int t = blockIdx.x * 256 + threadIdx.x;   // 32768 total
  float v; short* ph; short* pl; int o;
  if (t < 8192)       { int n = t >> 6, k = t & 63;                  v = w1[k*128+n]; ph = w1h; pl = w1l; o = t;  }
  else if (t < 24576) { int t2 = t-8192;  int n = t2 >> 7, k = t2 & 127; v = w2[k*128+n]; ph = w2h; pl = w2l; o = t2; }
  else                { int t3 = t-24576; int n = t3 >> 7, k = t3 & 127; v = w3[k*64+n];  ph = w3h; pl = w3l; o = t3; }
  unsigned short h = bf16_rne(v);
  ph[o] = (short)h;
  pl[o] = (short)bf16_rne(v - bf16_dec(h));
}

// ============ BN batch stats over gathered comb rows ============
__global__ __launch_bounds__(256) void bn_stats_kernel(
    const float* __restrict__ keys, const float* __restrict__ points,
    const float* __restrict__ feats, const unsigned short* __restrict__ idx,
    float* __restrict__ bnsum, float* __restrict__ bnsumsq) {
  __shared__ float ls[4][64];
  __shared__ float ls2[4][64];
  const int tid = threadIdx.x;
  const int c  = tid & 63;
  const int rl = tid >> 6;
  float s = 0.f, s2 = 0.f;
  for (int row = blockIdx.x * 4 + rl; row < ROWS; row += gridDim.x * 4) {
    int b = row >> 16;
    int rem = row & 65535;
    int q = rem >> 5;
    int n = idx[row];
    float v;
    if (c < 3) v = points[((size_t)b*NPTS + n)*3 + c] - keys[((size_t)b*KQ + q)*3 + c];
    else       v = feats[((size_t)b*NPTS + n)*CIN + (c-3)];
    s += v; s2 += v*v;
  }
  ls[rl][c] = s; ls2[rl][c] = s2;
  __syncthreads();
  if (tid < 64) {
    float ts  = ls[0][tid]+ls[1][tid]+ls[2][tid]+ls[3][tid];
    float ts2 = ls2[0][tid]+ls2[1][tid]+ls2[2][tid]+ls2[3][tid];
    atomicAdd(&bnsum[tid], ts);
    atomicAdd(&bnsumsq[tid], ts2);
  }
}

// bn_final: Ae[c][h] = gamma[c]*invstd[c] * attA[c][h]
__global__ void bn_final_kernel(const float* __restrict__ bnsum,
                                const float* __restrict__ bnsumsq,
                                const float* __restrict__ gamma,
                                const float* __restrict__ attA,
                                float* __restrict__ Ae) {
  const int t = threadIdx.x;
  if (t < 64) {
    const float invR = 1.f / (float)ROWS;
    float mean = bnsum[t] * invR;
    float var  = bnsumsq[t] * invR - mean * mean;
    float s = gamma[t] * rsqrtf(var + 1e-5f);
    float4 a = *(const float4*)(attA + t*4);
    float4 r; r.x = s*a.x; r.y = s*a.y; r.z = s*a.z; r.w = s*a.w;
    *(float4*)(Ae + t*4) = r;
  }
}

// ---------------- main-kernel LDS offsets (bytes) ----------------
#define L_W1   0        // [128][72] shorts  = 18432
#define L_W2H  18432    // [128][136] shorts = 34816
#define L_W2L  53248
#define L_W3H  88064    // [64][136] shorts  = 17408
#define L_W3L  105472
#define L_ACT  122880   // 4 waves x 8704 (bf16 [32][136] / f32 [32][68])
#define L_SCR  157696   // 4 waves x 1280 (EP f32[256] | IDXW int[32])
#define L_TOT  162816

// ============ per-wave GEMM: bf16 A (LDS), B from LDS (hi/lo optional) =======
template<int K, int LW, int NT, bool SPLIT, bool OUTF32, bool RELU>
__device__ __forceinline__ void wave_gemm_lds(short* ACTW,
    const short* WH, const short* WL,
    const float* __restrict__ bias, float* LATW, int lane) {
  const int lm = lane & 15, lq = lane >> 4;
  constexpr int KC = K / 32;
  bfrag a[2][KC];
#pragma unroll
  for (int mt = 0; mt < 2; ++mt)
#pragma unroll
    for (int kc = 0; kc < KC; ++kc)
      a[mt][kc] = *(const bfrag*)(ACTW + (mt*16 + lm)*136 + kc*32 + lq*8);
  ffrag acc[2][NT];
#pragma unroll
  for (int mt = 0; mt < 2; ++mt)
#pragma unroll
    for (int nt = 0; nt < NT; ++nt) acc[mt][nt] = (ffrag){0.f,0.f,0.f,0.f};
#pragma unroll
  for (int kc = 0; kc < KC; ++kc) {
#pragma unroll
    for (int nt = 0; nt < NT; ++nt) {
      const int wo = (nt*16 + lm)*LW + kc*32 + lq*8;
      bfrag bh = *(const bfrag*)(WH + wo);
      acc[0][nt] = __builtin_amdgcn_mfma_f32_16x16x32_bf16(a[0][kc], bh, acc[0][nt], 0,0,0);
      acc[1][nt] = __builtin_amdgcn_mfma_f32_16x16x32_bf16(a[1][kc], bh, acc[1][nt], 0,0,0);
      if (SPLIT) {
        bfrag bl = *(const bfrag*)(WL + wo);
        acc[0][nt] = __builtin_amdgcn_mfma_f32_16x16x32_bf16(a[0][kc], bl, acc[0][nt], 0,0,0);
        acc[1][nt] = __builtin_amdgcn_mfma_f32_16x16x32_bf16(a[1][kc], bl, acc[1][nt], 0,0,0);
      }
    }
  }
#pragma unroll
  for (int nt = 0; nt < NT; ++nt) {
    const int col = nt*16 + lm;
    const float bv = bias[col];
#pragma unroll
    for (int mt = 0; mt < 2; ++mt)
#pragma unroll
      for (int r = 0; r < 4; ++r) {
        const int row = mt*16 + lq*4 + r;
        float v = acc[mt][nt][r] + bv;
        if (RELU) v = fmaxf(v, 0.f);
        if (OUTF32) LATW[row*68 + col] = v;
        else        ACTW[row*136 + col] = (short)bf16_rne(v);
      }
  }
}

// ====== fused main: persistent blocks, weights in LDS, 1 query per wave ======
__global__ __launch_bounds__(256, 1) void main_kernel(
    const float* __restrict__ keys, const float* __restrict__ points,
    const float* __restrict__ feats, const unsigned short* __restrict__ idx,
    const short* __restrict__ w1h,
    const short* __restrict__ w2h, const short* __restrict__ w2l,
    const short* __restrict__ w3h, const short* __restrict__ w3l,
    const float* __restrict__ nx_b1, const float* __restrict__ nx_b2,
    const float* __restrict__ nx_b3,
    const float* __restrict__ AeG, float* __restrict__ out) {
  __shared__ __align__(16) char smem[L_TOT];
  const int tid = threadIdx.x;
  const int wid = tid >> 6, lane = tid & 63;

  short* SW1  = (short*)(smem + L_W1);
  short* SW2H = (short*)(smem + L_W2H);
  short* SW2L = (short*)(smem + L_W2L);
  short* SW3H = (short*)(smem + L_W3H);
  short* SW3L = (short*)(smem + L_W3L);
  short* ACTW = (short*)(smem + L_ACT + wid * 8704);
  float* LATW = (float*)(smem + L_ACT + wid * 8704);
  float* EP   = (float*)(smem + L_SCR + wid * 1280);
  int*  IDXW  = (int*)(EP + 256);

  // ---- stage all weights into LDS once (padded rows: bank-balanced b128) ----
#pragma unroll
  for (int t = tid; t < 1024; t += 256)      // W1 [128][64] -> [128][72]
    *(uint4*)(SW1 + (t>>3)*72 + (t&7)*8) = *(const uint4*)(w1h + t*8);
#pragma unroll
  for (int t = tid; t < 2048; t += 256)      // W2h [128][128] -> [128][136]
    *(uint4*)(SW2H + (t>>4)*136 + (t&15)*8) = *(const uint4*)(w2h + t*8);
#pragma unroll
  for (int t = tid; t < 2048; t += 256)
    *(uint4*)(SW2L + (t>>4)*136 + (t&15)*8) = *(const uint4*)(w2l + t*8);
#pragma unroll
  for (int t = tid; t < 1024; t += 256)      // W3 [64][128] -> [64][136]
    *(uint4*)(SW3H + (t>>4)*136 + (t&15)*8) = *(const uint4*)(w3h + t*8);
#pragma unroll
  for (int t = tid; t < 1024; t += 256)
    *(uint4*)(SW3L + (t>>4)*136 + (t&15)*8) = *(const uint4*)(w3l + t*8);
  __syncthreads();   // weights read-only hereafter; no block barriers below

  for (int grp = blockIdx.x; grp < BATCH*KQ/4; grp += 256) {
    const int g = grp * 4 + wid;               // this wave's query
    const int b = g >> 11;
    const float* Pb = points + (size_t)b * NPTS * 3;
    const float* Fb = feats  + (size_t)b * NPTS * CIN;

    if (lane < KNN) IDXW[lane] = (int)idx[(size_t)g*KNN + lane];
    WAVE_SYNC();

    // ---- gather comb -> bf16 A in LDS; e-partials on exact f32 values ----
    {
      const int rl = lane >> 1, half = lane & 1;
      const int n = IDXW[rl];
      const float* frow = Fb + (size_t)n * CIN;
      float v[32];
      if (half == 0) {
        v[0] = Pb[n*3+0] - keys[(size_t)g*3+0];
        v[1] = Pb[n*3+1] - keys[(size_t)g*3+1];
        v[2] = Pb[n*3+2] - keys[(size_t)g*3+2];
#pragma unroll
        for (int kk = 0; kk < 7; ++kk) {
          float4 t = ld4u(frow + kk*4);
          v[3+kk*4+0] = t.x; v[3+kk*4+1] = t.y; v[3+kk*4+2] = t.z; v[3+kk*4+3] = t.w;
        }
        v[31] = frow[28];
      } else {
#pragma unroll
        for (int kk = 0; kk < 8; ++kk) {
          float4 t = ld4u(frow + 29 + kk*4);
          v[kk*4+0] = t.x; v[kk*4+1] = t.y; v[kk*4+2] = t.z; v[kk*4+3] = t.w;
        }
      }
      float ep0 = 0.f, ep1 = 0.f, ep2 = 0.f, ep3 = 0.f;
#pragma unroll
      for (int cc = 0; cc < 32; ++cc) {
        float4 ae = *(const float4*)(AeG + (half*32 + cc)*4);
        ep0 = fmaf(v[cc], ae.x, ep0);
        ep1 = fmaf(v[cc], ae.y, ep1);
        ep2 = fmaf(v[cc], ae.z, ep2);
        ep3 = fmaf(v[cc], ae.w, ep3);
      }
#pragma unroll
      for (int k = 0; k < 4; ++k) {
        bfrag pk;
#pragma unroll
        for (int t = 0; t < 8; ++t) pk[t] = (short)bf16_rne(v[k*8 + t]);
        *(bfrag*)(ACTW + rl*136 + half*32 + k*8) = pk;
      }
      float4 e4; e4.x = ep0; e4.y = ep1; e4.z = ep2; e4.w = ep3;
      *(float4*)(EP + rl*8 + half*4) = e4;
    }
    WAVE_SYNC();

    // ---- parallel softmax over neighbors (n-constant logit terms cancel) ----
    {
      const int h = lane & 3, n0 = lane >> 2;    // lane covers n0 and n0+16
      float e0 = EP[n0*8 + h]      + EP[n0*8 + 4 + h];
      float e1 = EP[(n0+16)*8 + h] + EP[(n0+16)*8 + 4 + h];
      float m = fmaxf(e0, e1);
      m = fmaxf(m, __shfl_xor(m, 4));
      m = fmaxf(m, __shfl_xor(m, 8));
      m = fmaxf(m, __shfl_xor(m, 16));
      m = fmaxf(m, __shfl_xor(m, 32));
      float x0 = __expf(e0 - m), x1 = __expf(e1 - m);
      float s = x0 + x1;
      s += __shfl_xor(s, 4);
      s += __shfl_xor(s, 8);
      s += __shfl_xor(s, 16);
      s += __shfl_xor(s, 32);
      float inv = 1.f / s;
      EP[n0*8 + 4 + h]      = x0 * inv;          // WS[n][h] at EP[n*8+4+h]
      EP[(n0+16)*8 + 4 + h] = x1 * inv;
    }

    // ---- nx MLP on matrix cores: 64 ->128 relu ->128 relu ->64 ----
    wave_gemm_lds<64, 72, 8, false, false, true >(ACTW, SW1,  SW1,  nx_b1, LATW, lane);
    WAVE_SYNC();
    wave_gemm_lds<128,136, 8, true,  false, true >(ACTW, SW2H, SW2L, nx_b2, LATW, lane);
    WAVE_SYNC();
    wave_gemm_lds<128,136, 4, true,  true,  false>(ACTW, SW3H, SW3L, nx_b3, LATW, lane);
    WAVE_SYNC();

    // ---- epilogue: out[o][h] = sum_n lat[n][o] * w[n][h] ----
    {
      const int o = lane;
      float a0 = 0.f, a1 = 0.f, a2 = 0.f, a3 = 0.f;
#pragma unroll
      for (int n = 0; n < KNN; ++n) {
        float4 w = *(const float4*)(EP + n*8 + 4);   // broadcast read
        float l = LATW[n*68 + o];
        a0 = fmaf(l, w.x, a0);
        a1 = fmaf(l, w.y, a1);
        a2 = fmaf(l, w.z, a2);
        a3 = fmaf(l, w.w, a3);
      }
      float4 r; r.x = a0; r.y = a1; r.z = a2; r.w = a3;
      *(float4*)(out + ((size_t)g*64 + o)*4) = r;
    }
    WAVE_SYNC();   // LATW/EP reads drained before next iteration overwrites
  }
}

extern "C" void kernel_launch(void* const* d_in, const int* in_sizes, int n_in,
                              void* d_out, int out_size, void* d_ws, size_t ws_size,
                              hipStream_t stream) {
  const float* keys   = (const float*)d_in[0];
  const float* points = (const float*)d_in[1];
  const float* feats  = (const float*)d_in[2];
  const float* nx_w1  = (const float*)d_in[3];
  const float* nx_b1  = (const float*)d_in[4];
  const float* nx_w2  = (const float*)d_in[5];
  const float* nx_b2  = (const float*)d_in[6];
  const float* nx_w3  = (const float*)d_in[7];
  const float* nx_b3  = (const float*)d_in[8];
  // sx_w*/sx_b* (9..14), att_b (16), bn_beta (19): n-constant in softmax -> dead
  const float* att_w  = (const float*)d_in[15];
  const float* att_q  = (const float*)d_in[17];
  const float* gamma  = (const float*)d_in[18];
  float* out = (float*)d_out;

  char* ws = (char*)d_ws;
  unsigned short* idx = (unsigned short*)(ws + 0);
  float* bnsum   = (float*)(ws + OFF_SUM);
  float* bnsumsq = (float*)(ws + OFF_SUMSQ);
  float* attA    = (float*)(ws + OFF_ATTA);
  short* w1h = (short*)(ws + OFF_W1H);
  short* w1l = (short*)(ws + OFF_W1L);
  short* w2h = (short*)(ws + OFF_W2H);
  short* w2l = (short*)(ws + OFF_W2L);
  short* w3h = (short*)(ws + OFF_W3H);
  short* w3l = (short*)(ws + OFF_W3L);
  float* PT  = (float*)(ws + OFF_PT);
  float* Ae  = (float*)(ws + OFF_AE);

  hipMemsetAsync(bnsum, 0, 512, stream);
  prep_kernel<<<321, 256, 0, stream>>>(nx_w1, nx_w2, nx_w3, att_w, att_q, points,
                                       w1h, w1l, w2h, w2l, w3h, w3l, attA, PT);
  topk_kernel<<<BATCH*KQ/4, 256, 0, stream>>>(keys, PT, idx);
  bn_stats_kernel<<<1024, 256, 0, stream>>>(keys, points, feats, idx, bnsum, bnsumsq);
  bn_final_kernel<<<1, 64, 0, stream>>>(bnsum, bnsumsq, gamma, attA, Ae);
  main_kernel<<<256, 256, 0, stream>>>(keys, points, feats, idx,
      w1h, w2h, w2l, w3h, w3l, nx_b1, nx_b2, nx_b3, Ae, out);
}

// Round 5
// 303.771 us; speedup vs baseline: 2.3565x; 1.2141x over previous
//
#include <hip/hip_runtime.h>
#include <math.h>

#define BATCH 4
#define KQ    2048
#define NPTS  4096
#define CIN   61
#define KNN   32
#define ROWS  (BATCH*KQ*KNN)   // 262144

// ---------------- ws layout (bytes) ----------------
#define OFF_IDX    0         // u16 [262144] = 524288
#define OFF_ATTA   524288    // f32[256]
#define OFF_AE     525312    // f32[256]
#define OFF_W1H    526336    // bf16 [128][64]  = 16384
#define OFF_W2H    542720    // bf16 [128][128] = 32768
#define OFF_W2L    575488
#define OFF_W3H    608256    // bf16 [64][128]  = 16384
#define OFF_W3L    624640
#define OFF_PT     641024    // f32 [4][3][4096] = 196608
#define OFF_CNT    837632    // int [4*4096] = 65536   (memset region start)
#define OFF_RELACC 903168    // f32 [64][6] = 1536
#define OFF_BNSUM  904704    // f32[64]
#define OFF_BNSQ   904960    // f32[64]   end 905216; memset = 67584 B

typedef __attribute__((ext_vector_type(8))) short bfrag;   // 8 bf16
typedef __attribute__((ext_vector_type(4))) float ffrag;   // 4 f32 acc

__device__ __forceinline__ unsigned short bf16_rne(float x) {
  unsigned u = __float_as_uint(x);
  unsigned r = u + 0x7fffu + ((u >> 16) & 1u);
  return (unsigned short)(r >> 16);
}
__device__ __forceinline__ float bf16_dec(unsigned short h) {
  return __uint_as_float(((unsigned)h) << 16);
}
__device__ __forceinline__ float4 ld4u(const float* p) {  // 4B-aligned vec load
  float4 r; __builtin_memcpy(&r, p, 16); return r;
}

#define WAVE_SYNC() asm volatile("s_waitcnt lgkmcnt(0)" ::: "memory")

// ====== kNN: block-per-query, 16 d2-regs/lane, fused rel-stats + counts ======
__global__ __launch_bounds__(256) void topk_kernel(
    const float* __restrict__ keys, const float* __restrict__ PT,
    unsigned short* __restrict__ idx_out, int* __restrict__ cnt,
    float* __restrict__ relacc) {
  __shared__ int red[4];
  __shared__ int claim;
  __shared__ float wred[4][6];
  const int tid = threadIdx.x;
  const int lane = tid & 63, wid = tid >> 6;
  const int g = blockIdx.x;
  const int b = g >> 11;
  const float kx = keys[(size_t)g*3+0];
  const float ky = keys[(size_t)g*3+1];
  const float kz = keys[(size_t)g*3+2];
  const float* __restrict__ Px = PT + (size_t)b * 3 * NPTS;
  const float* __restrict__ Py = Px + NPTS;
  const float* __restrict__ Pz = Py + NPTS;
  unsigned u[16];
#pragma unroll
  for (int j = 0; j < 16; ++j) {
    int n = (j << 8) + tid;
    float dx = Px[n]-kx, dy = Py[n]-ky, dz = Pz[n]-kz;
    u[j] = __float_as_uint(dx*dx + dy*dy + dz*dz);  // >=0: uint order == float
  }
  if (tid == 0) claim = 0;
  unsigned lo = 0u, hi = 0x7f7fffffu;
  while (lo < hi) {
    unsigned mid = lo + ((hi - lo) >> 1);
    int c = 0;
#pragma unroll
    for (int j = 0; j < 16; ++j) c += (int)__popcll(__ballot(u[j] <= mid));
    if (lane == 0) red[wid] = c;
    __syncthreads();
    int total = red[0] + red[1] + red[2] + red[3];
    __syncthreads();
    if (total >= KNN) hi = mid; else lo = mid + 1;
  }
  const unsigned T = hi;   // exact 32nd-smallest d^2 bits
  unsigned short* dst = idx_out + (size_t)g * KNN;
  float sx=0.f, sy=0.f, sz=0.f, qx=0.f, qy=0.f, qz=0.f;
#pragma unroll
  for (int j = 0; j < 16; ++j) {
    if (u[j] <= T) {
      int pos = atomicAdd(&claim, 1);     // set semantics: order irrelevant
      if (pos < KNN) {
        int n = (j << 8) + tid;
        dst[pos] = (unsigned short)n;
        atomicAdd(&cnt[b*NPTS + n], 1);   // feats-stat multiplicity
        float dx = Px[n]-kx, dy = Py[n]-ky, dz = Pz[n]-kz;
        sx += dx; sy += dy; sz += dz;
        qx += dx*dx; qy += dy*dy; qz += dz*dz;
      }
    }
  }
  // block-reduce the 6 rel-stat partials
#pragma unroll
  for (int off = 32; off > 0; off >>= 1) {
    sx += __shfl_down(sx, off); sy += __shfl_down(sy, off); sz += __shfl_down(sz, off);
    qx += __shfl_down(qx, off); qy += __shfl_down(qy, off); qz += __shfl_down(qz, off);
  }
  if (lane == 0) {
    wred[wid][0]=sx; wred[wid][1]=sy; wred[wid][2]=sz;
    wred[wid][3]=qx; wred[wid][4]=qy; wred[wid][5]=qz;
  }
  __syncthreads();
  if (tid < 6) {
    float t6 = wred[0][tid]+wred[1][tid]+wred[2][tid]+wred[3][tid];
    atomicAdd(&relacc[(g & 63)*6 + tid], t6);   // 64 slots: low contention
  }
}

// ==== prep: weight conv (blocks 0..127) + attA (128) + SoA points (129..320) =
__global__ __launch_bounds__(256) void prep_kernel(
    const float* __restrict__ w1, const float* __restrict__ w2, const float* __restrict__ w3,
    const float* __restrict__ att_w, const float* __restrict__ att_q,
    const float* __restrict__ points,
    short* __restrict__ w1h,
    short* __restrict__ w2h, short* __restrict__ w2l,
    short* __restrict__ w3h, short* __restrict__ w3l,
    float* __restrict__ attA, float* __restrict__ PT) {
  if (blockIdx.x == 128) {   // attA[c][h] = sum_d att_w[c, h*64+d]*att_q[h,d]
    const int t = threadIdx.x, c = t >> 2, h = t & 3;
    float s = 0.f;
    for (int d = 0; d < 64; ++d) s += att_w[c*256 + h*64 + d] * att_q[h*64 + d];
    attA[c*4 + h] = s;
    return;
  }
  if (blockIdx.x >= 129) {   // points AoS -> SoA [b][c][n]
    int t = (blockIdx.x - 129) * 256 + threadIdx.x;   // < 49152
    int b = t / 12288, rem = t % 12288, c = rem >> 12, n = rem & 4095;
    PT[t] = points[((size_t)b*NPTS + n)*3 + c];
    return;
  }
  int t = blockIdx.x * 256 + threadIdx.x;   // 32768 total
  if (t < 8192) {            // w1: plain bf16 only
    int n = t >> 6, k = t & 63;
    w1h[t] = (short)bf16_rne(w1[k*128 + n]);
    return;
  }
  float v; short* ph; short* pl; int o;
  if (t < 24576) { int t2 = t-8192;  int n = t2 >> 7, k = t2 & 127; v = w2[k*128+n]; ph = w2h; pl = w2l; o = t2; }
  else           { int t3 = t-24576; int n = t3 >> 7, k = t3 & 127; v = w3[k*64+n];  ph = w3h; pl = w3l; o = t3; }
  unsigned short h = bf16_rne(v);
  ph[o] = (short)h;
  pl[o] = (short)bf16_rne(v - bf16_dec(h));
}

// ====== feats part of BN stats from selection counts (no gather) ======
__global__ __launch_bounds__(256) void feat_stats_kernel(
    const float* __restrict__ feats, const int* __restrict__ cnt,
    float* __restrict__ bnsum, float* __restrict__ bnsumsq) {
  __shared__ float ls[4][64];
  __shared__ float ls2[4][64];
  const int tid = threadIdx.x;
  const int c = tid & 63, rg = tid >> 6;
  const int b = blockIdx.x >> 5;
  const int n0 = (blockIdx.x & 31) * 128;
  float s = 0.f, s2 = 0.f;
  for (int n = n0 + rg; n < n0 + 128; n += 4) {
    float cn = (float)cnt[b*NPTS + n];
    if (c < CIN) {
      float v = feats[((size_t)b*NPTS + n)*CIN + c];
      s += cn*v; s2 += cn*v*v;
    }
  }
  ls[rg][c] = s; ls2[rg][c] = s2;
  __syncthreads();
  if (tid < CIN) {
    float ts  = ls[0][tid]+ls[1][tid]+ls[2][tid]+ls[3][tid];
    float ts2 = ls2[0][tid]+ls2[1][tid]+ls2[2][tid]+ls2[3][tid];
    atomicAdd(&bnsum[3+tid], ts);
    atomicAdd(&bnsumsq[3+tid], ts2);
  }
}

// bn_final: Ae[c][h] = gamma[c]*invstd[c]*attA[c][h]
__global__ void bn_final_kernel(const float* __restrict__ relacc,
                                const float* __restrict__ bnsum,
                                const float* __restrict__ bnsumsq,
                                const float* __restrict__ gamma,
                                const float* __restrict__ attA,
                                float* __restrict__ Ae) {
  const int t = threadIdx.x;
  if (t >= 64) return;
  float s, s2;
  if (t < 3) {
    s = 0.f; s2 = 0.f;
    for (int k = 0; k < 64; ++k) { s += relacc[k*6 + t]; s2 += relacc[k*6 + 3 + t]; }
  } else {
    s = bnsum[t]; s2 = bnsumsq[t];
  }
  const float invR = 1.f / (float)ROWS;
  float mean = s * invR;
  float var  = s2 * invR - mean * mean;
  float sc = gamma[t] * rsqrtf(var + 1e-5f);
  float4 a = ld4u(attA + t*4);
  float4 r; r.x = sc*a.x; r.y = sc*a.y; r.z = sc*a.z; r.w = sc*a.w;
  *(float4*)(Ae + t*4) = r;
}

// ---------------- main-kernel LDS offsets (bytes) ----------------
#define L_W1   0        // [128][72] shorts  = 18432 (plain bf16)
#define L_W2H  18432    // [128][136] shorts = 34816
#define L_W2L  53248
#define L_W3H  88064    // [64][136] shorts  = 17408
#define L_W3L  105472
#define L_ACT  122880   // 4 queries x 8704 (bf16 [32][136] / f32 [32][68])
#define L_EP   157696   // 4 x 512 (e-logits f32 [32][4])
#define L_WS   159744   // 4 x 512 (softmax w f32 [32][4])
#define L_AE   161792   // f32[256]
#define L_TOT  162816

// ====== per-wave GEMM on ONE 16-row m-tile; B from LDS (hi/lo optional) ======
template<int K, int LW, int NT, bool SPLIT, bool OUTF32, bool RELU>
__device__ __forceinline__ void wave_gemm(short* ACTq, int mt16,
    const short* WH, const short* WL,
    const float* __restrict__ bias, float* LATq, int lane) {
  const int lm = lane & 15, lq = lane >> 4;
  constexpr int KC = K / 32;
  bfrag a[KC];
#pragma unroll
  for (int kc = 0; kc < KC; ++kc)
    a[kc] = *(const bfrag*)(ACTq + (mt16 + lm)*136 + kc*32 + lq*8);
  ffrag acc[NT];
#pragma unroll
  for (int nt = 0; nt < NT; ++nt) acc[nt] = (ffrag){0.f,0.f,0.f,0.f};
#pragma unroll
  for (int kc = 0; kc < KC; ++kc) {
#pragma unroll
    for (int nt = 0; nt < NT; ++nt) {
      const int wo = (nt*16 + lm)*LW + kc*32 + lq*8;
      bfrag bh = *(const bfrag*)(WH + wo);
      acc[nt] = __builtin_amdgcn_mfma_f32_16x16x32_bf16(a[kc], bh, acc[nt], 0,0,0);
      if (SPLIT) {
        bfrag bl = *(const bfrag*)(WL + wo);
        acc[nt] = __builtin_amdgcn_mfma_f32_16x16x32_bf16(a[kc], bl, acc[nt], 0,0,0);
      }
    }
  }
#pragma unroll
  for (int nt = 0; nt < NT; ++nt) {
    const int col = nt*16 + lm;
    const float bv = bias[col];
#pragma unroll
    for (int r = 0; r < 4; ++r) {
      const int row = mt16 + lq*4 + r;
      float v = acc[nt][r] + bv;
      if (RELU) v = fmaxf(v, 0.f);
      if (OUTF32) LATq[row*68 + col] = v;
      else        ACTq[row*136 + col] = (short)bf16_rne(v);
    }
  }
}

// ====== fused main: 512 thr, 4 queries/block, 2 waves/query (m-tile split) ===
__global__ __launch_bounds__(512, 2) void main_kernel(
    const float* __restrict__ keys, const float* __restrict__ points,
    const float* __restrict__ feats, const unsigned short* __restrict__ idx,
    const short* __restrict__ w1h,
    const short* __restrict__ w2h, const short* __restrict__ w2l,
    const short* __restrict__ w3h, const short* __restrict__ w3l,
    const float* __restrict__ nx_b1, const float* __restrict__ nx_b2,
    const float* __restrict__ nx_b3,
    const float* __restrict__ AeG, float* __restrict__ out) {
  __shared__ __align__(16) char smem[L_TOT];
  const int tid = threadIdx.x;
  const int wid = tid >> 6, lane = tid & 63;
  const int qi = wid >> 1, mt = wid & 1, mt16 = mt << 4;

  short* SW1  = (short*)(smem + L_W1);
  short* SW2H = (short*)(smem + L_W2H);
  short* SW2L = (short*)(smem + L_W2L);
  short* SW3H = (short*)(smem + L_W3H);
  short* SW3L = (short*)(smem + L_W3L);
  short* ACTq = (short*)(smem + L_ACT + qi * 8704);
  float* LATq = (float*)(smem + L_ACT + qi * 8704);
  float* EPq  = (float*)(smem + L_EP  + qi * 512);
  float* WSq  = (float*)(smem + L_WS  + qi * 512);
  float* SAe  = (float*)(smem + L_AE);

  // ---- stage weights + Ae into LDS once ----
  for (int t = tid; t < 1024; t += 512)      // W1 [128][64] -> [128][72]
    *(uint4*)(SW1 + (t>>3)*72 + (t&7)*8) = *(const uint4*)(w1h + t*8);
  for (int t = tid; t < 2048; t += 512)      // W2 [128][128] -> [128][136]
    *(uint4*)(SW2H + (t>>4)*136 + (t&15)*8) = *(const uint4*)(w2h + t*8);
  for (int t = tid; t < 2048; t += 512)
    *(uint4*)(SW2L + (t>>4)*136 + (t&15)*8) = *(const uint4*)(w2l + t*8);
  for (int t = tid; t < 1024; t += 512)      // W3 [64][128] -> [64][136]
    *(uint4*)(SW3H + (t>>4)*136 + (t&15)*8) = *(const uint4*)(w3h + t*8);
  for (int t = tid; t < 1024; t += 512)
    *(uint4*)(SW3L + (t>>4)*136 + (t&15)*8) = *(const uint4*)(w3l + t*8);
  if (tid < 256) SAe[tid] = AeG[tid];
  __syncthreads();

  for (int grp = blockIdx.x; grp < BATCH*KQ/4; grp += 256) {
    const int g = grp * 4 + qi;
    const int b = g >> 11;
    const float* Pb = points + (size_t)b * NPTS * 3;
    const float* Fb = feats  + (size_t)b * NPTS * CIN;

    // ---- gather: wave covers its 16 rows; 4 lanes/row x 16 channels ----
    {
      const int rl = mt16 + (lane >> 2);      // row 0..31
      const int qtr = lane & 3;               // channel quarter
      const int n = (int)idx[(size_t)g*KNN + rl];
      const float* frow = Fb + (size_t)n * CIN;
      float v[16];
      if (qtr == 0) {
        v[0] = Pb[n*3+0] - keys[(size_t)g*3+0];
        v[1] = Pb[n*3+1] - keys[(size_t)g*3+1];
        v[2] = Pb[n*3+2] - keys[(size_t)g*3+2];
#pragma unroll
        for (int kk = 0; kk < 3; ++kk) {
          float4 t = ld4u(frow + kk*4);
          v[3+kk*4+0] = t.x; v[3+kk*4+1] = t.y; v[3+kk*4+2] = t.z; v[3+kk*4+3] = t.w;
        }
        v[15] = frow[12];
      } else {
        const int base = qtr*16 - 3;
#pragma unroll
        for (int kk = 0; kk < 4; ++kk) {
          float4 t = ld4u(frow + base + kk*4);
          v[kk*4+0] = t.x; v[kk*4+1] = t.y; v[kk*4+2] = t.z; v[kk*4+3] = t.w;
        }
      }
      // e-partials over this lane's 16 channels (exact f32)
      float ep0 = 0.f, ep1 = 0.f, ep2 = 0.f, ep3 = 0.f;
#pragma unroll
      for (int cc = 0; cc < 16; ++cc) {
        float4 ae = *(const float4*)(SAe + (qtr*16 + cc)*4);
        ep0 = fmaf(v[cc], ae.x, ep0);
        ep1 = fmaf(v[cc], ae.y, ep1);
        ep2 = fmaf(v[cc], ae.z, ep2);
        ep3 = fmaf(v[cc], ae.w, ep3);
      }
      ep0 += __shfl_xor(ep0, 1); ep1 += __shfl_xor(ep1, 1);
      ep2 += __shfl_xor(ep2, 1); ep3 += __shfl_xor(ep3, 1);
      ep0 += __shfl_xor(ep0, 2); ep1 += __shfl_xor(ep1, 2);
      ep2 += __shfl_xor(ep2, 2); ep3 += __shfl_xor(ep3, 2);
      // write bf16 A row segment
#pragma unroll
      for (int k = 0; k < 2; ++k) {
        bfrag pk;
#pragma unroll
        for (int t = 0; t < 8; ++t) pk[t] = (short)bf16_rne(v[k*8 + t]);
        *(bfrag*)(ACTq + rl*136 + qtr*16 + k*8) = pk;
      }
      if (qtr == 0) {
        float4 e4; e4.x = ep0; e4.y = ep1; e4.z = ep2; e4.w = ep3;
        *(float4*)(EPq + rl*4) = e4;
      }
    }
    __syncthreads();   // EP halves visible across the wave pair

    // ---- softmax over 32 neighbors (both waves compute; wave0 writes) ----
    {
      float e0 = EPq[lane];        // n = lane>>2,     h = lane&3
      float e1 = EPq[64 + lane];   // n = 16+(lane>>2)
      float m = fmaxf(e0, e1);
      m = fmaxf(m, __shfl_xor(m, 4));
      m = fmaxf(m, __shfl_xor(m, 8));
      m = fmaxf(m, __shfl_xor(m, 16));
      m = fmaxf(m, __shfl_xor(m, 32));
      float x0 = __expf(e0 - m), x1 = __expf(e1 - m);
      float s = x0 + x1;
      s += __shfl_xor(s, 4);
      s += __shfl_xor(s, 8);
      s += __shfl_xor(s, 16);
      s += __shfl_xor(s, 32);
      float inv = 1.f / s;
      if (mt == 0) { WSq[lane] = x0 * inv; WSq[64 + lane] = x1 * inv; }
    }

    // ---- nx MLP on matrix cores: 64 ->128 relu ->128 relu ->64 ----
    wave_gemm<64, 72, 8, false, false, true >(ACTq, mt16, SW1,  SW1,  nx_b1, LATq, lane);
    WAVE_SYNC();
    wave_gemm<128,136, 8, true,  false, true >(ACTq, mt16, SW2H, SW2L, nx_b2, LATq, lane);
    WAVE_SYNC();
    wave_gemm<128,136, 4, true,  true,  false>(ACTq, mt16, SW3H, SW3L, nx_b3, LATq, lane);
    __syncthreads();   // LATW halves + WS visible across the wave pair

    // ---- epilogue: wave mt covers 32 outputs x 2 heads per lane ----
    {
      const int o = (mt << 5) + (lane >> 1);
      const int hp = lane & 1;
      float a0 = 0.f, a1 = 0.f;
#pragma unroll
      for (int n = 0; n < KNN; ++n) {
        float l = LATq[n*68 + o];
        float2 w = *(const float2*)(WSq + n*4 + hp*2);
        a0 = fmaf(l, w.x, a0);
        a1 = fmaf(l, w.y, a1);
      }
      float2 r; r.x = a0; r.y = a1;
      *(float2*)(out + (size_t)g*256 + o*4 + hp*2) = r;
    }
    __syncthreads();   // drain reads before next iteration overwrites ACT/EP
  }
}

extern "C" void kernel_launch(void* const* d_in, const int* in_sizes, int n_in,
                              void* d_out, int out_size, void* d_ws, size_t ws_size,
                              hipStream_t stream) {
  const float* keys   = (const float*)d_in[0];
  const float* points = (const float*)d_in[1];
  const float* feats  = (const float*)d_in[2];
  const float* nx_w1  = (const float*)d_in[3];
  const float* nx_b1  = (const float*)d_in[4];
  const float* nx_w2  = (const float*)d_in[5];
  const float* nx_b2  = (const float*)d_in[6];
  const float* nx_w3  = (const float*)d_in[7];
  const float* nx_b3  = (const float*)d_in[8];
  // sx_w*/sx_b* (9..14), att_b (16), bn_beta (19): n-constant in softmax -> dead
  const float* att_w  = (const float*)d_in[15];
  const float* att_q  = (const float*)d_in[17];
  const float* gamma  = (const float*)d_in[18];
  float* out = (float*)d_out;

  char* ws = (char*)d_ws;
  unsigned short* idx = (unsigned short*)(ws + OFF_IDX);
  float* attA   = (float*)(ws + OFF_ATTA);
  float* Ae     = (float*)(ws + OFF_AE);
  short* w1h = (short*)(ws + OFF_W1H);
  short* w2h = (short*)(ws + OFF_W2H);
  short* w2l = (short*)(ws + OFF_W2L);
  short* w3h = (short*)(ws + OFF_W3H);
  short* w3l = (short*)(ws + OFF_W3L);
  float* PT  = (float*)(ws + OFF_PT);
  int*   cnt = (int*)(ws + OFF_CNT);
  float* relacc  = (float*)(ws + OFF_RELACC);
  float* bnsum   = (float*)(ws + OFF_BNSUM);
  float* bnsumsq = (float*)(ws + OFF_BNSQ);

  hipMemsetAsync(ws + OFF_CNT, 0, 67584, stream);   // cnt + relacc + bnsum/sq
  prep_kernel<<<321, 256, 0, stream>>>(nx_w1, nx_w2, nx_w3, att_w, att_q, points,
                                       w1h, w2h, w2l, w3h, w3l, attA, PT);
  topk_kernel<<<BATCH*KQ, 256, 0, stream>>>(keys, PT, idx, cnt, relacc);
  feat_stats_kernel<<<128, 256, 0, stream>>>(feats, cnt, bnsum, bnsumsq);
  bn_final_kernel<<<1, 64, 0, stream>>>(relacc, bnsum, bnsumsq, gamma, attA, Ae);
  main_kernel<<<256, 512, 0, stream>>>(keys, points, feats, idx,
      w1h, w2h, w2l, w3h, w3l, nx_b1, nx_b2, nx_b3, Ae, out);
}

// Round 6
// 239.950 us; speedup vs baseline: 2.9833x; 1.2660x over previous
//
#include <hip/hip_runtime.h>
#include <math.h>

#define BATCH 4
#define KQ    2048
#define NPTS  4096
#define CIN   61
#define KNN   32
#define ROWS  (BATCH*KQ*KNN)   // 262144

// ---------------- ws layout (bytes) ----------------
#define OFF_IDX    0         // u16 [262144] = 524288
#define OFF_ATTA   524288    // f32[256]
#define OFF_AE     525312    // f32[256]
#define OFF_W1F    526336    // bf16 frag-major [4t][4kc][64lane][8] = 16384
#define OFF_W2F    542720    // bf16 frag-major [4][8][64][8] = 32768
#define OFF_W3F    575488    // bf16 frag-major [2][8][64][8] = 16384
#define OFF_PT     591872    // f32 [4][3][4096] = 196608
#define OFF_CNT    788480    // int [4*4096] = 65536   (memset region start)
#define OFF_RELACC 854016    // f32 [64][6] = 1536
#define OFF_BNSUM  855552    // f32[64]
#define OFF_BNSQ   855808    // f32[64]   memset = 67584 B from OFF_CNT

typedef __attribute__((ext_vector_type(8)))  short bfrag;   // 8 bf16
typedef __attribute__((ext_vector_type(16))) float cfrag;   // 32x32 acc

__device__ __forceinline__ unsigned short bf16_rne(float x) {
  unsigned u = __float_as_uint(x);
  unsigned r = u + 0x7fffu + ((u >> 16) & 1u);
  return (unsigned short)(r >> 16);
}
__device__ __forceinline__ float4 ld4u(const float* p) {  // 4B-aligned vec load
  float4 r; __builtin_memcpy(&r, p, 16); return r;
}

// ====== kNN: bound-and-compact exact select, 2 block barriers ======
__global__ __launch_bounds__(256) void topk_kernel(
    const float* __restrict__ keys, const float* __restrict__ PT,
    unsigned short* __restrict__ idx_out, int* __restrict__ cnt,
    float* __restrict__ relacc) {
  __shared__ unsigned hiw[4];
  __shared__ int blkcnt;
  __shared__ unsigned VAL[384];
  __shared__ int IDXL[384];
  const int tid = threadIdx.x;
  const int lane = tid & 63, wid = tid >> 6;
  const int g = blockIdx.x;
  const int b = g >> 11;
  const float kx = keys[(size_t)g*3+0];
  const float ky = keys[(size_t)g*3+1];
  const float kz = keys[(size_t)g*3+2];
  const float* __restrict__ Px = PT + (size_t)b * 3 * NPTS;
  const float* __restrict__ Py = Px + NPTS;
  const float* __restrict__ Pz = Py + NPTS;
  unsigned u[16];
  unsigned lmin = 0xffffffffu;
#pragma unroll
  for (int j = 0; j < 16; ++j) {
    int n = (j << 8) + tid;
    float dx = Px[n]-kx, dy = Py[n]-ky, dz = Pz[n]-kz;
    u[j] = __float_as_uint(dx*dx + dy*dy + dz*dz);  // >=0: uint order == float
    lmin = min(lmin, u[j]);
  }
  // wave min of lane-mins (search lower bound)
  unsigned wmin = lmin;
#pragma unroll
  for (int off = 1; off < 64; off <<= 1)
    wmin = min(wmin, (unsigned)__shfl_xor((int)wmin, off));
  // hi_w = 32nd smallest of the 64 lane-mins (upper bound for global T)
  unsigned lo = wmin, hi = 0x7f7fffffu;
  while (lo < hi) {
    unsigned mid = lo + ((hi - lo) >> 1);
    int c = (int)__popcll(__ballot(lmin <= mid));
    if (c >= KNN) hi = mid; else lo = mid + 1;
  }
  if (lane == 0) hiw[wid] = hi;
  if (tid == 0) blkcnt = 0;
  __syncthreads();
  const unsigned hib = min(min(hiw[0], hiw[1]), min(hiw[2], hiw[3]));
  const unsigned long long lmask = (1ull << lane) - 1ull;
  // compact candidates (all global top-32 have d2 <= hib)
#pragma unroll
  for (int j = 0; j < 16; ++j) {
    bool p = (u[j] <= hib);
    unsigned long long m = __ballot(p);
    int tot = (int)__popcll(m);
    int base = 0;
    if (lane == 0 && tot) base = atomicAdd(&blkcnt, tot);
    base = __shfl(base, 0);
    if (p) {
      int pos = base + (int)__popcll(m & lmask);
      if (pos < 384) { VAL[pos] = u[j]; IDXL[pos] = (j << 8) + tid; }
    }
  }
  __syncthreads();
  if (wid != 0) return;
  const int mcount = min(blkcnt, 384);
  // wave0: exact select over compacted list
  unsigned e[6];
#pragma unroll
  for (int s = 0; s < 6; ++s) {
    int ei = s*64 + lane;
    e[s] = (ei < mcount) ? VAL[ei] : 0xffffffffu;
  }
  lo = 0u; hi = hib;
  while (lo < hi) {
    unsigned mid = lo + ((hi - lo) >> 1);
    int c = 0;
#pragma unroll
    for (int s = 0; s < 6; ++s) c += (int)__popcll(__ballot(e[s] <= mid));
    if (c >= KNN) hi = mid; else lo = mid + 1;
  }
  const unsigned T = hi;
  // extraction + fused rel BN-stats + per-point selection counts
  unsigned short* dst = idx_out + (size_t)g * KNN;
  float sx=0.f, sy=0.f, sz=0.f, qx=0.f, qy=0.f, qz=0.f;
  int base2 = 0;
#pragma unroll
  for (int s = 0; s < 6; ++s) {
    bool p = (e[s] <= T);
    unsigned long long m = __ballot(p);
    if (p) {
      int pos = base2 + (int)__popcll(m & lmask);
      if (pos < KNN) {
        int n = IDXL[s*64 + lane];
        dst[pos] = (unsigned short)n;
        atomicAdd(&cnt[b*NPTS + n], 1);
        float dx = Px[n]-kx, dy = Py[n]-ky, dz = Pz[n]-kz;
        sx += dx; sy += dy; sz += dz;
        qx += dx*dx; qy += dy*dy; qz += dz*dz;
      }
    }
    base2 += (int)__popcll(m);
  }
#pragma unroll
  for (int off = 32; off > 0; off >>= 1) {
    sx += __shfl_down(sx, off); sy += __shfl_down(sy, off); sz += __shfl_down(sz, off);
    qx += __shfl_down(qx, off); qy += __shfl_down(qy, off); qz += __shfl_down(qz, off);
  }
  if (lane == 0) {
    float* ra = &relacc[(g & 63)*6];
    atomicAdd(&ra[0], sx); atomicAdd(&ra[1], sy); atomicAdd(&ra[2], sz);
    atomicAdd(&ra[3], qx); atomicAdd(&ra[4], qy); atomicAdd(&ra[5], qz);
  }
}

// ==== prep: frag-major weights (0..127) + attA (128) + SoA points (129..320) =
__global__ __launch_bounds__(256) void prep_kernel(
    const float* __restrict__ w1, const float* __restrict__ w2, const float* __restrict__ w3,
    const float* __restrict__ att_w, const float* __restrict__ att_q,
    const float* __restrict__ points,
    short* __restrict__ w1f, short* __restrict__ w2f, short* __restrict__ w3f,
    float* __restrict__ attA, float* __restrict__ PT) {
  if (blockIdx.x == 128) {   // attA[c][h] = sum_d att_w[c, h*64+d]*att_q[h,d]
    const int t = threadIdx.x, c = t >> 2, h = t & 3;
    float s = 0.f;
    for (int d = 0; d < 64; ++d) s += att_w[c*256 + h*64 + d] * att_q[h*64 + d];
    attA[c*4 + h] = s;
    return;
  }
  if (blockIdx.x >= 129) {   // points AoS -> SoA [b][c][n]
    int t = (blockIdx.x - 129) * 256 + threadIdx.x;   // < 49152
    int b = t / 12288, rem = t % 12288, c = rem >> 12, n = rem & 4095;
    PT[t] = points[((size_t)b*NPTS + n)*3 + c];
    return;
  }
  // frag-major: out[((tile*KC+kc)*64+lane)*8+j] = W[k][nh],
  // nh = tile*32+(lane&31), k = kc*16+(lane>>5)*8+j
  int t = blockIdx.x * 256 + threadIdx.x;   // 32768 total
  if (t < 8192) {            // W1: NH=128, K=64, KC=4
    int j = t & 7, lane = (t >> 3) & 63, tk = t >> 9;
    int kc = tk & 3, tile = tk >> 2;
    int nh = tile*32 + (lane & 31), k = kc*16 + (lane >> 5)*8 + j;
    w1f[t] = (short)bf16_rne(w1[k*128 + nh]);
  } else if (t < 24576) {    // W2: NH=128, K=128, KC=8
    int t2 = t - 8192;
    int j = t2 & 7, lane = (t2 >> 3) & 63, tk = t2 >> 9;
    int kc = tk & 7, tile = tk >> 3;
    int nh = tile*32 + (lane & 31), k = kc*16 + (lane >> 5)*8 + j;
    w2f[t2] = (short)bf16_rne(w2[k*128 + nh]);
  } else {                   // W3: NH=64, K=128, KC=8
    int t3 = t - 24576;
    int j = t3 & 7, lane = (t3 >> 3) & 63, tk = t3 >> 9;
    int kc = tk & 7, tile = tk >> 3;
    int nh = tile*32 + (lane & 31), k = kc*16 + (lane >> 5)*8 + j;
    w3f[t3] = (short)bf16_rne(w3[k*64 + nh]);
  }
}

// ====== feats part of BN stats from selection counts (no gather) ======
__global__ __launch_bounds__(256) void feat_stats_kernel(
    const float* __restrict__ feats, const int* __restrict__ cnt,
    float* __restrict__ bnsum, float* __restrict__ bnsumsq) {
  __shared__ float ls[4][64];
  __shared__ float ls2[4][64];
  const int tid = threadIdx.x;
  const int c = tid & 63, rg = tid >> 6;
  const int b = blockIdx.x >> 5;
  const int n0 = (blockIdx.x & 31) * 128;
  float s = 0.f, s2 = 0.f;
  for (int n = n0 + rg; n < n0 + 128; n += 4) {
    float cn = (float)cnt[b*NPTS + n];
    if (c < CIN) {
      float v = feats[((size_t)b*NPTS + n)*CIN + c];
      s += cn*v; s2 += cn*v*v;
    }
  }
  ls[rg][c] = s; ls2[rg][c] = s2;
  __syncthreads();
  if (tid < CIN) {
    float ts  = ls[0][tid]+ls[1][tid]+ls[2][tid]+ls[3][tid];
    float ts2 = ls2[0][tid]+ls2[1][tid]+ls2[2][tid]+ls2[3][tid];
    atomicAdd(&bnsum[3+tid], ts);
    atomicAdd(&bnsumsq[3+tid], ts2);
  }
}

// bn_final: Ae[c][h] = gamma[c]*invstd[c]*attA[c][h]
__global__ void bn_final_kernel(const float* __restrict__ relacc,
                                const float* __restrict__ bnsum,
                                const float* __restrict__ bnsumsq,
                                const float* __restrict__ gamma,
                                const float* __restrict__ attA,
                                float* __restrict__ Ae) {
  const int t = threadIdx.x;
  if (t >= 64) return;
  float s, s2;
  if (t < 3) {
    s = 0.f; s2 = 0.f;
    for (int k = 0; k < 64; ++k) { s += relacc[k*6 + t]; s2 += relacc[k*6 + 3 + t]; }
  } else {
    s = bnsum[t]; s2 = bnsumsq[t];
  }
  const float invR = 1.f / (float)ROWS;
  float mean = s * invR;
  float var  = s2 * invR - mean * mean;
  float sc = gamma[t] * rsqrtf(var + 1e-5f);
  float4 a = ld4u(attA + t*4);
  float4 r; r.x = sc*a.x; r.y = sc*a.y; r.z = sc*a.z; r.w = sc*a.w;
  *(float4*)(Ae + t*4) = r;
}

// ---------------- main-kernel LDS offsets (bytes) ----------------
#define L_W1F 0        // 16384
#define L_W2F 16384    // 32768
#define L_W3F 49152    // 16384
#define L_B1  65536    // 512
#define L_B2  66048    // 512
#define L_B3  66560    // 256
#define L_AE  66816    // 1024
#define L_ACT 67840    // 8 x 8704 (bf16 [32][136] / f32 [32][68]; pad unused)
#define L_EPX 137472   // 8 x 32 x 8 f32 = 8192
#define L_TOT 145664

// per-wave GEMM over its n-tiles: A = weight frags (frag-major stream),
// B = activation frags (held in regs), C stored transposed-packed.
template<int KC, bool F32OUT>
__device__ __forceinline__ void gemm_part(const short* __restrict__ WF,
    const float* __restrict__ BIAS, short* ACTq, float* LATq,
    const bfrag* B, int tile0, int ntiles, int m, int q, int lane) {
#pragma unroll
  for (int t = 0; t < ntiles; ++t) {
    const int tile = tile0 + t;
    cfrag acc;
#pragma unroll
    for (int i = 0; i < 16; ++i) acc[i] = 0.f;
#pragma unroll
    for (int kc = 0; kc < KC; ++kc) {
      bfrag a = *(const bfrag*)(WF + ((tile*KC + kc)*64 + lane)*8);
      acc = __builtin_amdgcn_mfma_f32_32x32x16_bf16(a, B[kc], acc, 0, 0, 0);
    }
#pragma unroll
    for (int p = 0; p < 4; ++p) {
      const int nh = tile*32 + p*8 + q*4;
      float4 bv = *(const float4*)(BIAS + nh);
      if (F32OUT) {
        float4 o;
        o.x = acc[4*p+0] + bv.x; o.y = acc[4*p+1] + bv.y;
        o.z = acc[4*p+2] + bv.z; o.w = acc[4*p+3] + bv.w;
        *(float4*)(LATq + m*68 + nh) = o;
      } else {
        short4 s;
        s.x = (short)bf16_rne(fmaxf(acc[4*p+0] + bv.x, 0.f));
        s.y = (short)bf16_rne(fmaxf(acc[4*p+1] + bv.y, 0.f));
        s.z = (short)bf16_rne(fmaxf(acc[4*p+2] + bv.z, 0.f));
        s.w = (short)bf16_rne(fmaxf(acc[4*p+3] + bv.w, 0.f));
        *(short4*)(ACTq + m*136 + nh) = s;
      }
    }
  }
}

// ====== fused main: 1024 thr, 8 queries/block, wave-pair per query, =========
// ====== 32x32x16 MFMA with operand swap, frag-major weights in LDS ==========
__global__ __launch_bounds__(1024, 4) void main_kernel(
    const float* __restrict__ keys, const float* __restrict__ points,
    const float* __restrict__ feats, const unsigned short* __restrict__ idx,
    const short* __restrict__ w1f, const short* __restrict__ w2f,
    const short* __restrict__ w3f,
    const float* __restrict__ nx_b1, const float* __restrict__ nx_b2,
    const float* __restrict__ nx_b3,
    const float* __restrict__ AeG, float* __restrict__ out) {
  __shared__ __align__(16) char smem[L_TOT];
  const int tid = threadIdx.x;
  const int wid = tid >> 6, lane = tid & 63;
  const int pairq = wid >> 1;     // query slot 0..7
  const int wv = wid & 1;         // wave within pair (n-dim split)
  const int m = lane & 31, q = lane >> 5;

  short* SW1 = (short*)(smem + L_W1F);
  short* SW2 = (short*)(smem + L_W2F);
  short* SW3 = (short*)(smem + L_W3F);
  float* SB1 = (float*)(smem + L_B1);
  float* SB2 = (float*)(smem + L_B2);
  float* SB3 = (float*)(smem + L_B3);
  float* SAe = (float*)(smem + L_AE);
  short* ACTq = (short*)(smem + L_ACT + pairq * 8704);
  float* LATq = (float*)(smem + L_ACT + pairq * 8704);
  float* EPX  = (float*)(smem + L_EPX) + pairq * 256;   // [32][8]

  // ---- stage weights/biases/Ae into LDS once ----
  ((uint4*)SW1)[tid] = ((const uint4*)w1f)[tid];                 // 1024 x 16B
  ((uint4*)SW2)[tid] = ((const uint4*)w2f)[tid];
  ((uint4*)SW2)[tid + 1024] = ((const uint4*)w2f)[tid + 1024];
  ((uint4*)SW3)[tid] = ((const uint4*)w3f)[tid];
  if (tid < 128) SB1[tid] = nx_b1[tid];
  else if (tid < 256) SB2[tid-128] = nx_b2[tid-128];
  else if (tid < 320) SB3[tid-256] = nx_b3[tid-256];
  else if (tid < 576) SAe[tid-320] = AeG[tid-320];
  __syncthreads();

  for (int grp = blockIdx.x; grp < BATCH*KQ/8; grp += 256) {
    const int g = grp * 8 + pairq;
    const int b = g >> 11;
    const float* Fb = feats + (size_t)b * NPTS * CIN;

    // ---- gather: lane covers (row m, 16 channels at c0) ----
    {
      const int c0 = wv*32 + q*16;
      const int n = (int)idx[(size_t)g*KNN + m];
      const float* frow = Fb + (size_t)n * CIN;
      float v[16];
      if (wv == 0 && q == 0) {
        const float* Pb = points + (size_t)b * NPTS * 3;
        v[0] = Pb[n*3+0] - keys[(size_t)g*3+0];
        v[1] = Pb[n*3+1] - keys[(size_t)g*3+1];
        v[2] = Pb[n*3+2] - keys[(size_t)g*3+2];
#pragma unroll
        for (int kk = 0; kk < 3; ++kk) {
          float4 t = ld4u(frow + kk*4);
          v[3+kk*4+0] = t.x; v[3+kk*4+1] = t.y; v[3+kk*4+2] = t.z; v[3+kk*4+3] = t.w;
        }
        v[15] = frow[12];
      } else {
        const int base = c0 - 3;
#pragma unroll
        for (int kk = 0; kk < 4; ++kk) {
          float4 t = ld4u(frow + base + kk*4);
          v[kk*4+0] = t.x; v[kk*4+1] = t.y; v[kk*4+2] = t.z; v[kk*4+3] = t.w;
        }
      }
      // e-partials over this lane's 16 channels (exact f32)
      float ep0 = 0.f, ep1 = 0.f, ep2 = 0.f, ep3 = 0.f;
#pragma unroll
      for (int cc = 0; cc < 16; ++cc) {
        float4 ae = *(const float4*)(SAe + (c0 + cc)*4);
        ep0 = fmaf(v[cc], ae.x, ep0);
        ep1 = fmaf(v[cc], ae.y, ep1);
        ep2 = fmaf(v[cc], ae.z, ep2);
        ep3 = fmaf(v[cc], ae.w, ep3);
      }
      ep0 += __shfl_xor(ep0, 32); ep1 += __shfl_xor(ep1, 32);
      ep2 += __shfl_xor(ep2, 32); ep3 += __shfl_xor(ep3, 32);
      // write bf16 comb segment (2 x b128)
#pragma unroll
      for (int k = 0; k < 2; ++k) {
        bfrag pk;
#pragma unroll
        for (int t = 0; t < 8; ++t) pk[t] = (short)bf16_rne(v[k*8 + t]);
        *(bfrag*)(ACTq + m*136 + c0 + k*8) = pk;
      }
      if (q == 0) {
        float4 e4; e4.x = ep0; e4.y = ep1; e4.z = ep2; e4.w = ep3;
        *(float4*)(EPX + m*8 + wv*4) = e4;
      }
    }
    __syncthreads();   // B1: gather + e-partials complete

    // ---- softmax over 32 neighbors (wave 0 of pair only; n-const terms cancel)
    if (wv == 0) {
      const int h0 = q*2;
      float ea = EPX[m*8 + h0]     + EPX[m*8 + 4 + h0];
      float eb = EPX[m*8 + h0 + 1] + EPX[m*8 + 5 + h0];
      float ma = ea, mb = eb;
#pragma unroll
      for (int off = 1; off < 32; off <<= 1) {
        ma = fmaxf(ma, __shfl_xor(ma, off));
        mb = fmaxf(mb, __shfl_xor(mb, off));
      }
      float xa = __expf(ea - ma), xb = __expf(eb - mb);
      float sa = xa, sb = xb;
#pragma unroll
      for (int off = 1; off < 32; off <<= 1) {
        sa += __shfl_xor(sa, off);
        sb += __shfl_xor(sb, off);
      }
      EPX[m*8 + h0]     = xa / sa;    // WS[n][h] overwrites slots 0..3
      EPX[m*8 + h0 + 1] = xb / sb;
    }

    // ---- GEMM1: 64 -> 128 relu ----
    {
      bfrag B4[4];
#pragma unroll
      for (int kc = 0; kc < 4; ++kc)
        B4[kc] = *(const bfrag*)(ACTq + m*136 + kc*16 + q*8);
      __syncthreads();   // B2: comb loaded by all; safe to overwrite
      gemm_part<4, false>(SW1, SB1, ACTq, LATq, B4, wv*2, 2, m, q, lane);
    }
    __syncthreads();     // B3: h1 complete
    // ---- GEMM2: 128 -> 128 relu ----
    {
      bfrag B8[8];
#pragma unroll
      for (int kc = 0; kc < 8; ++kc)
        B8[kc] = *(const bfrag*)(ACTq + m*136 + kc*16 + q*8);
      __syncthreads();   // B4
      gemm_part<8, false>(SW2, SB2, ACTq, LATq, B8, wv*2, 2, m, q, lane);
    }
    __syncthreads();     // B5: h2 complete
    // ---- GEMM3: 128 -> 64, f32 out (lat) ----
    {
      bfrag C8[8];
#pragma unroll
      for (int kc = 0; kc < 8; ++kc)
        C8[kc] = *(const bfrag*)(ACTq + m*136 + kc*16 + q*8);
      __syncthreads();   // B6
      gemm_part<8, true>(SW3, SB3, ACTq, LATq, C8, wv, 1, m, q, lane);
    }
    __syncthreads();     // B7: lat + WS ready

    // ---- epilogue: out[o][h] = sum_n lat[n][o]*w[n][h] ----
    {
      const int oi = wv*64 + lane;
      const int o = oi >> 1, hp = oi & 1;
      float a0 = 0.f, a1 = 0.f;
#pragma unroll
      for (int n2 = 0; n2 < KNN; ++n2) {
        float l = LATq[n2*68 + o];
        float2 w2v = *(const float2*)(EPX + n2*8 + hp*2);
        a0 = fmaf(l, w2v.x, a0);
        a1 = fmaf(l, w2v.y, a1);
      }
      float2 r; r.x = a0; r.y = a1;
      *(float2*)(out + (size_t)g*256 + o*4 + hp*2) = r;
    }
    __syncthreads();     // B8: drain before next iter overwrites ACT/EPX
  }
}

extern "C" void kernel_launch(void* const* d_in, const int* in_sizes, int n_in,
                              void* d_out, int out_size, void* d_ws, size_t ws_size,
                              hipStream_t stream) {
  const float* keys   = (const float*)d_in[0];
  const float* points = (const float*)d_in[1];
  const float* feats  = (const float*)d_in[2];
  const float* nx_w1  = (const float*)d_in[3];
  const float* nx_b1  = (const float*)d_in[4];
  const float* nx_w2  = (const float*)d_in[5];
  const float* nx_b2  = (const float*)d_in[6];
  const float* nx_w3  = (const float*)d_in[7];
  const float* nx_b3  = (const float*)d_in[8];
  // sx_w*/sx_b* (9..14), att_b (16), bn_beta (19): n-constant in softmax -> dead
  const float* att_w  = (const float*)d_in[15];
  const float* att_q  = (const float*)d_in[17];
  const float* gamma  = (const float*)d_in[18];
  float* out = (float*)d_out;

  char* ws = (char*)d_ws;
  unsigned short* idx = (unsigned short*)(ws + OFF_IDX);
  float* attA = (float*)(ws + OFF_ATTA);
  float* Ae   = (float*)(ws + OFF_AE);
  short* w1f  = (short*)(ws + OFF_W1F);
  short* w2f  = (short*)(ws + OFF_W2F);
  short* w3f  = (short*)(ws + OFF_W3F);
  float* PT   = (float*)(ws + OFF_PT);
  int*   cnt  = (int*)(ws + OFF_CNT);
  float* relacc  = (float*)(ws + OFF_RELACC);
  float* bnsum   = (float*)(ws + OFF_BNSUM);
  float* bnsumsq = (float*)(ws + OFF_BNSQ);

  hipMemsetAsync(ws + OFF_CNT, 0, 67584, stream);   // cnt + relacc + bnsum/sq
  prep_kernel<<<321, 256, 0, stream>>>(nx_w1, nx_w2, nx_w3, att_w, att_q, points,
                                       w1f, w2f, w3f, attA, PT);
  topk_kernel<<<BATCH*KQ, 256, 0, stream>>>(keys, PT, idx, cnt, relacc);
  feat_stats_kernel<<<128, 256, 0, stream>>>(feats, cnt, bnsum, bnsumsq);
  bn_final_kernel<<<1, 64, 0, stream>>>(relacc, bnsum, bnsumsq, gamma, attA, Ae);
  main_kernel<<<256, 1024, 0, stream>>>(keys, points, feats, idx,
      w1f, w2f, w3f, nx_b1, nx_b2, nx_b3, Ae, out);
}